// Round 4
// baseline (514.853 us; speedup 1.0000x reference)
//
#include <hip/hip_runtime.h>
#include <hip/hip_bf16.h>
#include <stdint.h>

typedef __bf16 bf16;
typedef __bf16 bf16x8 __attribute__((ext_vector_type(8)));
typedef __bf16 bf16x4 __attribute__((ext_vector_type(4)));
typedef float f32x4 __attribute__((ext_vector_type(4)));

#define GLOAD_LDS16(gptr, lptr)                                                        \
  __builtin_amdgcn_global_load_lds((const __attribute__((address_space(1))) void*)(gptr), \
                                   (__attribute__((address_space(3))) void*)(lptr), 16, 0, 0)

// ---------------- weight cast fp32 -> bf16 ----------------
__global__ __launch_bounds__(256) void cast_f2b(const float* __restrict__ in,
                                                bf16* __restrict__ out, int n) {
  int i = (blockIdx.x * 256 + threadIdx.x) * 4;
  if (i >= n) return;
  const float4 v = *(const float4*)(in + i);
  bf16x4 o;
  o[0] = (bf16)v.x; o[1] = (bf16)v.y; o[2] = (bf16)v.z; o[3] = (bf16)v.w;
  *(bf16x4*)(out + i) = o;
}

// ---------------- prep: cast+transpose x -> xbT[n][c], 2x2 maxpool -> pxT[m][c] ----
__global__ __launch_bounds__(256) void prep_kernel(const float* __restrict__ x,
                                                   bf16* __restrict__ xbT,
                                                   bf16* __restrict__ pxT) {
  const int b = blockIdx.y;
  x   += (size_t)b * 1024 * 4096;
  xbT += (size_t)b * 4096 * 1024;
  pxT += (size_t)b * 1024 * 1024;
  const int bid = blockIdx.x;
  const int h0 = bid & 31, ct = bid >> 5;
  const int tid = threadIdx.x;
  __shared__ float tile[32][129];
  const float* xs = x + (size_t)(ct * 32) * 4096 + h0 * 128;
#pragma unroll
  for (int e = 0; e < 16; ++e) {
    int idx = e * 256 + tid;
    int c = idx >> 7, n = idx & 127;
    tile[c][n] = xs[(size_t)c * 4096 + n];
  }
  __syncthreads();
  bf16* xo = xbT + (size_t)(h0 * 128) * 1024 + ct * 32;
#pragma unroll
  for (int e = 0; e < 16; ++e) {
    int idx = e * 256 + tid;
    int n = idx >> 5, c = idx & 31;
    xo[(size_t)n * 1024 + c] = (bf16)tile[c][n];
  }
  bf16* po = pxT + (size_t)(h0 * 32) * 1024 + ct * 32;
#pragma unroll
  for (int e = 0; e < 4; ++e) {
    int idx = e * 256 + tid;
    int m = idx >> 5, c = idx & 31;
    float v = fmaxf(fmaxf(tile[c][2 * m], tile[c][2 * m + 1]),
                    fmaxf(tile[c][64 + 2 * m], tile[c][64 + 2 * m + 1]));
    po[(size_t)m * 1024 + c] = (bf16)v;
  }
}

// ---------------- bt-flavor GEMM: C[MxN] = A[MxK] * B[NxK]^T ----------------
// EPI: 1 bf16 store of (acc + bias[col]) * scale; 2 bf16 + bias[row];
//      4 fp32 store + bias[row] + resid
template <int EPI>
__global__ __launch_bounds__(256) void gemm_bt(
    const bf16* __restrict__ A, long long sA, int lda,
    const bf16* __restrict__ B, long long sB, int ldb,
    void* __restrict__ Cv, long long sC, int ldc, int K,
    const float* __restrict__ bias,
    const float* __restrict__ resid, long long sResid, float scale) {
  const int z = blockIdx.z;
  A += (size_t)z * sA;
  B += (size_t)z * sB;
  const int tid = threadIdx.x;
  const int w = tid >> 6, lane = tid & 63;
  const int r16 = lane & 15, q4 = lane >> 4;
  const long long tileM = (long long)blockIdx.x * 128;
  const long long tileN = (long long)blockIdx.y * 128;

  __shared__ bf16 As[2][128 * 32];
  __shared__ bf16 Bs[2][128 * 32];

  f32x4 acc[4][4] = {};

  const int srow = tid >> 2;
  const int soff = (tid & 3) * 16;
  const char* Ag0 = (const char*)A + ((size_t)(tileM + srow) * lda) * 2 + soff;
  const char* Bg0 = (const char*)B + ((size_t)(tileN + srow) * ldb) * 2 + soff;
  const size_t arow64 = (size_t)64 * lda * 2;
  const size_t brow64 = (size_t)64 * ldb * 2;

  auto stage = [&](int buf, int k0) {
    const char* a = Ag0 + (size_t)k0 * 2;
    const char* b = Bg0 + (size_t)k0 * 2;
    bf16* al = &As[buf][w * 512];
    bf16* bl = &Bs[buf][w * 512];
    GLOAD_LDS16(a, al);
    GLOAD_LDS16(a + arow64, al + 2048);
    GLOAD_LDS16(b, bl);
    GLOAD_LDS16(b + brow64, bl + 2048);
  };

  const int wr = (w >> 1) * 64, wc = (w & 1) * 64;
  const int nt = K >> 5;
  stage(0, 0);
  __syncthreads();
  int cur = 0;
  for (int t = 0; t < nt; ++t) {
    if (t + 1 < nt) stage(cur ^ 1, (t + 1) * 32);
    bf16x8 af[4], bfv[4];
#pragma unroll
    for (int f = 0; f < 4; ++f) {
      af[f]  = *(const bf16x8*)&As[cur][(wr + f * 16 + r16) * 32 + q4 * 8];
      bfv[f] = *(const bf16x8*)&Bs[cur][(wc + f * 16 + r16) * 32 + q4 * 8];
    }
#pragma unroll
    for (int i = 0; i < 4; ++i)
#pragma unroll
      for (int j = 0; j < 4; ++j)
        acc[i][j] = __builtin_amdgcn_mfma_f32_16x16x32_bf16(af[i], bfv[j], acc[i][j], 0, 0, 0);
    __syncthreads();
    cur ^= 1;
  }

  if constexpr (EPI == 4) {
    float* C = (float*)Cv + (size_t)z * sC;
#pragma unroll
    for (int i = 0; i < 4; ++i) {
      const int row0 = (int)tileM + wr + i * 16 + q4 * 4;
#pragma unroll
      for (int j = 0; j < 4; ++j) {
        const int col = (int)tileN + wc + j * 16 + r16;
#pragma unroll
        for (int r = 0; r < 4; ++r) {
          float v = acc[i][j][r];
          v += bias[row0 + r];
          v += resid[(size_t)z * sResid + (size_t)(row0 + r) * ldc + col];
          C[(size_t)(row0 + r) * ldc + col] = v;
        }
      }
    }
  } else {
    bf16* C = (bf16*)Cv + (size_t)z * sC;
#pragma unroll
    for (int i = 0; i < 4; ++i) {
      const int row0 = (int)tileM + wr + i * 16 + q4 * 4;
#pragma unroll
      for (int j = 0; j < 4; ++j) {
        const int col = (int)tileN + wc + j * 16 + r16;
        float badd = 0.f;
        if constexpr (EPI == 1) badd = bias[col];
#pragma unroll
        for (int r = 0; r < 4; ++r) {
          float v = acc[i][j][r];
          if constexpr (EPI == 1) v = (v + badd) * scale;
          if constexpr (EPI == 2) v += bias[row0 + r];
          C[(size_t)(row0 + r) * ldc + col] = (bf16)v;
        }
      }
    }
  }
}

// ---------------- fused attention v3 ----------------
// Q = thetaT [z][4096][512] (scale pre-folded), K = phiT [z][1024][512],
// G = g [z][512][1024], T out [z][4096][512] bf16.
// Block: 64 q-rows, 8 waves. Q persistent in LDS (swizzled). K and G are
// L2-resident (1MB each per batch) -> loaded DIRECTLY into register
// fragments per lane (no LDS, no barriers). P double-buffered in LDS;
// exactly ONE barrier per m-chunk (write->read fence for P).
__global__ __launch_bounds__(512, 1) void attn_kernel(
    const bf16* __restrict__ Qg, const bf16* __restrict__ Kg,
    const bf16* __restrict__ Gg, bf16* __restrict__ Tg) {
  const int z = blockIdx.y;
  const bf16* Q  = Qg + (size_t)z * (4096 * 512) + (size_t)blockIdx.x * (64 * 512);
  const bf16* Kp = Kg + (size_t)z * (1024 * 512);
  const bf16* Gp = Gg + (size_t)z * (512 * 1024);
  bf16* T = Tg + (size_t)z * (4096 * 512) + (size_t)blockIdx.x * (64 * 512);

  const int tid = threadIdx.x;
  const int w = tid >> 6, lane = tid & 63;
  const int r16 = lane & 15, q4 = lane >> 4;

  __shared__ bf16 QL[64 * 512];       // 64KB, slot-swizzled
  __shared__ bf16 P_lds[2][64 * 128]; // 32KB dbuf, byte ^= (row&7)<<4
  __shared__ float rowsum4[4][64];    // per-col-slice partial rowsums

  if (tid < 256) ((float*)rowsum4)[tid] = 0.f;

  const int wr  = (w >> 2) * 32;   // q-row group: 0 or 32
  const int wcq = (w & 3) * 32;    // QK col slice (m within chunk)

  // ---- Q prologue: rows w, w+8, ..., w+56; pre-swizzled source (involution) ----
#pragma unroll
  for (int r8 = 0; r8 < 8; ++r8) {
    const int row = w + r8 * 8;
    GLOAD_LDS16((const char*)(Q + (size_t)row * 512 + ((lane ^ w) << 3)),
                &QL[row * 512]);
  }
  __syncthreads();  // fence QL prologue + rowsum init

  f32x4 acc_o[2][8] = {};

  // per-lane fragment base pointers
  const bf16* Kb = Kp + (size_t)(wcq + r16) * 512 + q4 * 8;          // + mc*65536 + j*8192 + t*32
  const bf16* Gb = Gp + (size_t)((w & 3) * 64 + r16) * 1024 + q4 * 8; // + h*262144 + jj*16384 + mc*128 + s*32

  for (int mc = 0; mc < 8; ++mc) {
    // ---- QK phase: S-chunk(64x128) = Q . K-chunk^T over d=512, K in regs ----
    const bf16* Kc = Kb + (size_t)mc * (128 * 512);
    f32x4 acc_s[2][2] = {};
    bf16x8 kf[2][2];
    kf[0][0] = *(const bf16x8*)(Kc);
    kf[0][1] = *(const bf16x8*)(Kc + 16 * 512);
#pragma unroll
    for (int t = 0; t < 16; ++t) {
      if (t + 1 < 16) {
        const bf16* Kn = Kc + (t + 1) * 32;
        kf[(t + 1) & 1][0] = *(const bf16x8*)(Kn);
        kf[(t + 1) & 1][1] = *(const bf16x8*)(Kn + 16 * 512);
      }
      const int slotB = (((t * 4 + q4) ^ (r16 & 7)) << 4);
      bf16x8 af[2];
      af[0] = *(const bf16x8*)((const char*)QL + (size_t)(wr + r16) * 1024 + slotB);
      af[1] = *(const bf16x8*)((const char*)QL + (size_t)(wr + 16 + r16) * 1024 + slotB);
#pragma unroll
      for (int i = 0; i < 2; ++i)
#pragma unroll
        for (int j = 0; j < 2; ++j)
          acc_s[i][j] = __builtin_amdgcn_mfma_f32_16x16x32_bf16(af[i], kf[t & 1][j], acc_s[i][j], 0, 0, 0);
    }
    // ---- epilogue: p = exp(s) (no max: |logits| small); P -> LDS dbuf; rowsum ----
    bf16* Pc = P_lds[mc & 1];
    float prow[2][4] = {};
#pragma unroll
    for (int i = 0; i < 2; ++i) {
      const int row0 = wr + i * 16 + q4 * 4;
#pragma unroll
      for (int j = 0; j < 2; ++j) {
        const int col = wcq + j * 16 + r16;
#pragma unroll
        for (int r = 0; r < 4; ++r) {
          float p = __expf(acc_s[i][j][r]);
          prow[i][r] += p;
          int byteoff = ((row0 + r) * 128 + col) * 2;
          byteoff ^= ((row0 + r) & 7) << 4;
          *(bf16*)((char*)Pc + byteoff) = (bf16)p;
        }
      }
    }
#pragma unroll
    for (int i = 0; i < 2; ++i)
#pragma unroll
      for (int r = 0; r < 4; ++r) {
        float v = prow[i][r];
        v += __shfl_xor(v, 1);
        v += __shfl_xor(v, 2);
        v += __shfl_xor(v, 4);
        v += __shfl_xor(v, 8);
        if (r16 == 0) rowsum4[w & 3][wr + i * 16 + q4 * 4 + r] += v;
      }
    __syncthreads();  // P writes visible to all waves
    // ---- PV phase: O += P(64x128) . G(512x128)^T, G in regs ----
    const bf16* Gc = Gb + mc * 128;
    bf16x8 gf[2][4];
#pragma unroll
    for (int jj = 0; jj < 4; ++jj)
      gf[0][jj] = *(const bf16x8*)(Gc + (size_t)jj * (16 * 1024));
#pragma unroll
    for (int u = 0; u < 8; ++u) {
      if (u + 1 < 8) {
        const int hn = (u + 1) >> 2, sn = (u + 1) & 3;
        const bf16* Gn = Gc + (size_t)hn * (256 * 1024) + sn * 32;
#pragma unroll
        for (int jj = 0; jj < 4; ++jj)
          gf[(u + 1) & 1][jj] = *(const bf16x8*)(Gn + (size_t)jj * (16 * 1024));
      }
      const int s = u & 3;
      bf16x8 pf[2];
#pragma unroll
      for (int i = 0; i < 2; ++i) {
        const int row = wr + i * 16 + r16;
        int byteoff = row * 256 + (s * 32 + q4 * 8) * 2;
        byteoff ^= (row & 7) << 4;
        pf[i] = *(const bf16x8*)((const char*)Pc + byteoff);
      }
#pragma unroll
      for (int i = 0; i < 2; ++i)
#pragma unroll
        for (int jj = 0; jj < 4; ++jj)
          acc_o[i][(u >> 2) * 4 + jj] =
              __builtin_amdgcn_mfma_f32_16x16x32_bf16(pf[i], gf[u & 1][jj], acc_o[i][(u >> 2) * 4 + jj], 0, 0, 0);
    }
  }
  // ---- final: divide by total rowsum, store bf16 (all rowsum writes precede
  //      the last in-loop barrier) ----
#pragma unroll
  for (int i = 0; i < 2; ++i) {
    const int row0 = wr + i * 16 + q4 * 4;
    float inv[4];
#pragma unroll
    for (int r = 0; r < 4; ++r) {
      float rs = rowsum4[0][row0 + r] + rowsum4[1][row0 + r] +
                 rowsum4[2][row0 + r] + rowsum4[3][row0 + r];
      inv[r] = 1.0f / rs;
    }
#pragma unroll
    for (int idx = 0; idx < 8; ++idx) {
      const int col = (idx >> 2) * 256 + (w & 3) * 64 + (idx & 3) * 16 + r16;
#pragma unroll
      for (int r = 0; r < 4; ++r)
        T[(size_t)(row0 + r) * 512 + col] = (bf16)(acc_o[i][idx][r] * inv[r]);
    }
  }
}

// ---------------- launch ----------------
extern "C" void kernel_launch(void* const* d_in, const int* in_sizes, int n_in,
                              void* d_out, int out_size, void* d_ws, size_t ws_size,
                              hipStream_t stream) {
  const float* x  = (const float*)d_in[0];
  const float* Wt = (const float*)d_in[1];
  const float* bt = (const float*)d_in[2];
  const float* Wp = (const float*)d_in[3];
  const float* bp = (const float*)d_in[4];
  const float* Wg = (const float*)d_in[5];
  const float* bg = (const float*)d_in[6];
  const float* Wo = (const float*)d_in[7];
  const float* bo = (const float*)d_in[8];
  float* out = (float*)d_out;

  const size_t MB = 1024ull * 1024ull;
  char* ws = (char*)d_ws;
  bf16* WtB = (bf16*)(ws + 0 * MB);
  bf16* WpB = (bf16*)(ws + 1 * MB);
  bf16* WgB = (bf16*)(ws + 2 * MB);
  bf16* WoB = (bf16*)(ws + 3 * MB);

  cast_f2b<<<512, 256, 0, stream>>>(Wt, WtB, 512 * 1024);
  cast_f2b<<<512, 256, 0, stream>>>(Wp, WpB, 512 * 1024);
  cast_f2b<<<512, 256, 0, stream>>>(Wg, WgB, 512 * 1024);
  cast_f2b<<<512, 256, 0, stream>>>(Wo, WoB, 1024 * 512);

  const float SCALE = 0.044194173824159216f;  // 512^-0.5, folded into theta

  auto run_tail = [&](int nb, int b0, bf16* pxT, bf16* phiT, bf16* g,
                      bf16* thetaT, bf16* tT) {
    gemm_bt<1><<<dim3(8, 4, nb), 256, 0, stream>>>(pxT, 1024ll * 1024, 1024, WpB, 0, 1024,
                                                   phiT, 1024ll * 512, 512, 1024,
                                                   bp, nullptr, 0, 1.f);
    gemm_bt<2><<<dim3(4, 8, nb), 256, 0, stream>>>(WgB, 0, 1024, pxT, 1024ll * 1024, 1024,
                                                   g, 512ll * 1024, 1024, 1024,
                                                   bg, nullptr, 0, 1.f);
    attn_kernel<<<dim3(64, nb), 512, 0, stream>>>(thetaT, phiT, g, tT);
    gemm_bt<4><<<dim3(8, 32, nb), 256, 0, stream>>>(WoB, 0, 512, tT, 4096ll * 512, 512,
                                                    out + (size_t)b0 * 1024 * 4096,
                                                    1024ll * 4096, 4096, 512,
                                                    bo, x + (size_t)b0 * 1024 * 4096,
                                                    1024ll * 4096, 1.f);
  };

  if (ws_size >= 164 * MB) {
    bf16* pxT    = (bf16*)(ws + 4 * MB);     // 16MB
    bf16* phiT   = (bf16*)(ws + 20 * MB);    // 8MB
    bf16* g      = (bf16*)(ws + 28 * MB);    // 8MB
    bf16* thetaT = (bf16*)(ws + 36 * MB);    // 32MB
    bf16* tT     = (bf16*)(ws + 68 * MB);    // 32MB
    bf16* xbT    = (bf16*)(ws + 100 * MB);   // 64MB
    prep_kernel<<<dim3(1024, 8), 256, 0, stream>>>(x, xbT, pxT);
    gemm_bt<1><<<dim3(32, 4, 8), 256, 0, stream>>>(xbT, 4096ll * 1024, 1024, WtB, 0, 1024,
                                                   thetaT, 4096ll * 512, 512, 1024,
                                                   bt, nullptr, 0, SCALE);
    run_tail(8, 0, pxT, phiT, g, thetaT, tT);
  } else if (ws_size >= 108 * MB) {
    bf16* pxT    = (bf16*)(ws + 4 * MB);
    bf16* phiT   = (bf16*)(ws + 20 * MB);
    bf16* g      = (bf16*)(ws + 28 * MB);
    bf16* thetaT = (bf16*)(ws + 36 * MB);
    bf16* tT     = (bf16*)(ws + 68 * MB);
    bf16* xbT    = (bf16*)(ws + 100 * MB);   // 8MB, per-batch
    for (int b = 0; b < 8; ++b) {
      prep_kernel<<<dim3(1024, 1), 256, 0, stream>>>(x + (size_t)b * 1024 * 4096, xbT,
                                                     pxT + (size_t)b * 1024 * 1024);
      gemm_bt<1><<<dim3(32, 4, 1), 256, 0, stream>>>(xbT, 0, 1024, WtB, 0, 1024,
                                                     thetaT + (size_t)b * 4096 * 512, 0, 512,
                                                     1024, bt, nullptr, 0, SCALE);
    }
    run_tail(8, 0, pxT, phiT, g, thetaT, tT);
  } else {
    bf16* pxT    = (bf16*)(ws + 4 * MB);     // 2MB
    bf16* phiT   = (bf16*)(ws + 6 * MB);     // 1MB
    bf16* g      = (bf16*)(ws + 7 * MB);     // 1MB
    bf16* thetaT = (bf16*)(ws + 8 * MB);     // 4MB
    bf16* tT     = (bf16*)(ws + 12 * MB);    // 4MB
    bf16* xbT    = (bf16*)(ws + 16 * MB);    // 8MB
    for (int b = 0; b < 8; ++b) {
      prep_kernel<<<dim3(1024, 1), 256, 0, stream>>>(x + (size_t)b * 1024 * 4096, xbT, pxT);
      gemm_bt<1><<<dim3(32, 4, 1), 256, 0, stream>>>(xbT, 0, 1024, WtB, 0, 1024,
                                                     thetaT, 0, 512, 1024,
                                                     bt, nullptr, 0, SCALE);
      run_tail(1, b, pxT, phiT, g, thetaT, tT);
    }
  }
}

// Round 5
// 408.979 us; speedup vs baseline: 1.2589x; 1.2589x over previous
//
#include <hip/hip_runtime.h>
#include <hip/hip_bf16.h>
#include <stdint.h>

typedef __bf16 bf16;
typedef __bf16 bf16x8 __attribute__((ext_vector_type(8)));
typedef __bf16 bf16x4 __attribute__((ext_vector_type(4)));
typedef float f32x4 __attribute__((ext_vector_type(4)));

#define GLOAD_LDS16(gptr, lptr)                                                        \
  __builtin_amdgcn_global_load_lds((const __attribute__((address_space(1))) void*)(gptr), \
                                   (__attribute__((address_space(3))) void*)(lptr), 16, 0, 0)

// ---------------- weight cast fp32 -> bf16 ----------------
__global__ __launch_bounds__(256) void cast_f2b(const float* __restrict__ in,
                                                bf16* __restrict__ out, int n) {
  int i = (blockIdx.x * 256 + threadIdx.x) * 4;
  if (i >= n) return;
  const float4 v = *(const float4*)(in + i);
  bf16x4 o;
  o[0] = (bf16)v.x; o[1] = (bf16)v.y; o[2] = (bf16)v.z; o[3] = (bf16)v.w;
  *(bf16x4*)(out + i) = o;
}

// ---------------- prep: cast+transpose x -> xbT[n][c], 2x2 maxpool -> pxT[m][c] ----
__global__ __launch_bounds__(256) void prep_kernel(const float* __restrict__ x,
                                                   bf16* __restrict__ xbT,
                                                   bf16* __restrict__ pxT) {
  const int b = blockIdx.y;
  x   += (size_t)b * 1024 * 4096;
  xbT += (size_t)b * 4096 * 1024;
  pxT += (size_t)b * 1024 * 1024;
  const int bid = blockIdx.x;
  const int h0 = bid & 31, ct = bid >> 5;
  const int tid = threadIdx.x;
  __shared__ float tile[32][129];
  const float* xs = x + (size_t)(ct * 32) * 4096 + h0 * 128;
#pragma unroll
  for (int e = 0; e < 16; ++e) {
    int idx = e * 256 + tid;
    int c = idx >> 7, n = idx & 127;
    tile[c][n] = xs[(size_t)c * 4096 + n];
  }
  __syncthreads();
  bf16* xo = xbT + (size_t)(h0 * 128) * 1024 + ct * 32;
#pragma unroll
  for (int e = 0; e < 16; ++e) {
    int idx = e * 256 + tid;
    int n = idx >> 5, c = idx & 31;
    xo[(size_t)n * 1024 + c] = (bf16)tile[c][n];
  }
  bf16* po = pxT + (size_t)(h0 * 32) * 1024 + ct * 32;
#pragma unroll
  for (int e = 0; e < 4; ++e) {
    int idx = e * 256 + tid;
    int m = idx >> 5, c = idx & 31;
    float v = fmaxf(fmaxf(tile[c][2 * m], tile[c][2 * m + 1]),
                    fmaxf(tile[c][64 + 2 * m], tile[c][64 + 2 * m + 1]));
    po[(size_t)m * 1024 + c] = (bf16)v;
  }
}

// ---------------- bt-flavor GEMM: C[MxN] = A[MxK] * B[NxK]^T ----------------
// EPI: 1 bf16 store of (acc + bias[col]) * scale; 2 bf16 + bias[row];
//      4 fp32 store + bias[row] + resid
template <int EPI>
__global__ __launch_bounds__(256) void gemm_bt(
    const bf16* __restrict__ A, long long sA, int lda,
    const bf16* __restrict__ B, long long sB, int ldb,
    void* __restrict__ Cv, long long sC, int ldc, int K,
    const float* __restrict__ bias,
    const float* __restrict__ resid, long long sResid, float scale) {
  const int z = blockIdx.z;
  A += (size_t)z * sA;
  B += (size_t)z * sB;
  const int tid = threadIdx.x;
  const int w = tid >> 6, lane = tid & 63;
  const int r16 = lane & 15, q4 = lane >> 4;
  const long long tileM = (long long)blockIdx.x * 128;
  const long long tileN = (long long)blockIdx.y * 128;

  __shared__ bf16 As[2][128 * 32];
  __shared__ bf16 Bs[2][128 * 32];

  f32x4 acc[4][4] = {};

  const int srow = tid >> 2;
  const int soff = (tid & 3) * 16;
  const char* Ag0 = (const char*)A + ((size_t)(tileM + srow) * lda) * 2 + soff;
  const char* Bg0 = (const char*)B + ((size_t)(tileN + srow) * ldb) * 2 + soff;
  const size_t arow64 = (size_t)64 * lda * 2;
  const size_t brow64 = (size_t)64 * ldb * 2;

  auto stage = [&](int buf, int k0) {
    const char* a = Ag0 + (size_t)k0 * 2;
    const char* b = Bg0 + (size_t)k0 * 2;
    bf16* al = &As[buf][w * 512];
    bf16* bl = &Bs[buf][w * 512];
    GLOAD_LDS16(a, al);
    GLOAD_LDS16(a + arow64, al + 2048);
    GLOAD_LDS16(b, bl);
    GLOAD_LDS16(b + brow64, bl + 2048);
  };

  const int wr = (w >> 1) * 64, wc = (w & 1) * 64;
  const int nt = K >> 5;
  stage(0, 0);
  __syncthreads();
  int cur = 0;
  for (int t = 0; t < nt; ++t) {
    if (t + 1 < nt) stage(cur ^ 1, (t + 1) * 32);
    bf16x8 af[4], bfv[4];
#pragma unroll
    for (int f = 0; f < 4; ++f) {
      af[f]  = *(const bf16x8*)&As[cur][(wr + f * 16 + r16) * 32 + q4 * 8];
      bfv[f] = *(const bf16x8*)&Bs[cur][(wc + f * 16 + r16) * 32 + q4 * 8];
    }
#pragma unroll
    for (int i = 0; i < 4; ++i)
#pragma unroll
      for (int j = 0; j < 4; ++j)
        acc[i][j] = __builtin_amdgcn_mfma_f32_16x16x32_bf16(af[i], bfv[j], acc[i][j], 0, 0, 0);
    __syncthreads();
    cur ^= 1;
  }

  if constexpr (EPI == 4) {
    float* C = (float*)Cv + (size_t)z * sC;
#pragma unroll
    for (int i = 0; i < 4; ++i) {
      const int row0 = (int)tileM + wr + i * 16 + q4 * 4;
#pragma unroll
      for (int j = 0; j < 4; ++j) {
        const int col = (int)tileN + wc + j * 16 + r16;
#pragma unroll
        for (int r = 0; r < 4; ++r) {
          float v = acc[i][j][r];
          v += bias[row0 + r];
          v += resid[(size_t)z * sResid + (size_t)(row0 + r) * ldc + col];
          C[(size_t)(row0 + r) * ldc + col] = v;
        }
      }
    }
  } else {
    bf16* C = (bf16*)Cv + (size_t)z * sC;
#pragma unroll
    for (int i = 0; i < 4; ++i) {
      const int row0 = (int)tileM + wr + i * 16 + q4 * 4;
#pragma unroll
      for (int j = 0; j < 4; ++j) {
        const int col = (int)tileN + wc + j * 16 + r16;
        float badd = 0.f;
        if constexpr (EPI == 1) badd = bias[col];
#pragma unroll
        for (int r = 0; r < 4; ++r) {
          float v = acc[i][j][r];
          if constexpr (EPI == 1) v = (v + badd) * scale;
          if constexpr (EPI == 2) v += bias[row0 + r];
          C[(size_t)(row0 + r) * ldc + col] = (bf16)v;
        }
      }
    }
  }
}

// ---------------- fused attention v5: counted-vmcnt pipelined staging ----------
// Q = thetaT [z][4096][512] (scale pre-folded), K = phiT [z][1024][512],
// G = g [z][512][1024], T out [z][4096][512] bf16.
// 64 q-rows/block, 8 waves. Q persistent in LDS. K/G staged by global_load_lds
// into ring-3 buffers; per body step: issue stage(s+2), s_waitcnt vmcnt(N)
// (N = outstanding ops of stages s+1,s+2; never 0), s_barrier, ds_read + MFMA,
// s_barrier. Stream per mc: 16 K-bodies (4 MFMA) + 8 G-bodies (8 MFMA).
__global__ __launch_bounds__(512, 1) void attn_kernel(
    const bf16* __restrict__ Qg, const bf16* __restrict__ Kg,
    const bf16* __restrict__ Gg, bf16* __restrict__ Tg) {
  const int z = blockIdx.y;
  const bf16* Q  = Qg + (size_t)z * (4096 * 512) + (size_t)blockIdx.x * (64 * 512);
  const bf16* Kp = Kg + (size_t)z * (1024 * 512);
  const bf16* Gp = Gg + (size_t)z * (512 * 1024);
  bf16* T = Tg + (size_t)z * (4096 * 512) + (size_t)blockIdx.x * (64 * 512);

  const int tid = threadIdx.x;
  const int w = tid >> 6, lane = tid & 63;
  const int r16 = lane & 15, q4 = lane >> 4;

  __shared__ bf16 QL[64 * 512];     // 64KB, slot-swizzled (16B slot ^ w)
  __shared__ bf16 Pl[64 * 128];     // 16KB, byte ^= (row&7)<<4
  __shared__ bf16 Kst[3][4096];     // 3x8KB  [128 r][32 k], slot16 ^= (r>>1)&3
  __shared__ bf16 Gst[3][8192];     // 3x16KB [256 r][32 m], slot16 ^= (r>>1)&3
  __shared__ float rowsum4[4][64];

  const int wr  = (w >> 2) * 32;   // q-row group
  const int wcq = (w & 3) * 32;    // QK m-col slice

  const int lr = lane >> 2;        // 0..15
  const int rK = (w << 4) + lr;    // K stage row 0..127
  const int qK = (lane & 3) ^ ((rK >> 1) & 3);

  auto issueK = [&](int mcc, int t) {
    GLOAD_LDS16((const char*)(Kp + ((size_t)(mcc * 128 + rK) * 512) + t * 32 + qK * 8),
                &Kst[t % 3][w * 512]);
  };
  auto issueG = [&](int mcc, int j) {  // j=0..7: h=j>>2 (d-half), s4=j&3 (m sub)
    const int h = j >> 2, s4 = j & 3;
#pragma unroll
    for (int e = 0; e < 2; ++e) {
      const int r = (w << 5) + (e << 4) + lr;           // 0..255
      const int q = (lane & 3) ^ ((r >> 1) & 3);
      GLOAD_LDS16((const char*)(Gp + ((size_t)(h * 256 + r) * 1024) + mcc * 128 + s4 * 32 + q * 8),
                  &Gst[j % 3][w * 1024 + e * 512]);
    }
  };

  // ---- prologue: Q (8 ops), K0, K1; wait Q done (2 newest may fly) ----
#pragma unroll
  for (int r8 = 0; r8 < 8; ++r8) {
    const int row = w + r8 * 8;
    GLOAD_LDS16((const char*)(Q + (size_t)row * 512 + ((lane ^ w) << 3)),
                &QL[row * 512]);
  }
  issueK(0, 0);
  issueK(0, 1);
  if (tid < 256) ((float*)rowsum4)[tid] = 0.f;
  asm volatile("s_waitcnt vmcnt(2)" ::: "memory");
  __builtin_amdgcn_s_barrier();

  f32x4 acc_o[2][8] = {};

  for (int mc = 0; mc < 8; ++mc) {
    f32x4 acc_s[2][2] = {};
#pragma unroll
    for (int s = 0; s < 24; ++s) {
      // issue stage s+2 of stream [K0..K15, G0..G7, next-mc K0,K1]
      const int sp = s + 2;
      if (sp < 16) issueK(mc, sp);
      else if (sp < 24) issueG(mc, sp - 16);
      else if (mc + 1 < 8) issueK(mc + 1, sp - 24);
      // wait: stage s complete; stages s+1, s+2 stay in flight
      const int n = (s <= 13) ? 2 : (s == 14) ? 3 : (s <= 21) ? 4 : (s == 22) ? 3 : 2;
      if (n == 2)      asm volatile("s_waitcnt vmcnt(2)" ::: "memory");
      else if (n == 3) asm volatile("s_waitcnt vmcnt(3)" ::: "memory");
      else             asm volatile("s_waitcnt vmcnt(4)" ::: "memory");
      __builtin_amdgcn_s_barrier();

      if (s < 16) {
        // ---- QK body t = s: 4 MFMA ----
        const int t = s;
        const int slotB = (((t * 4 + q4) ^ (r16 & 7)) << 4);
        bf16x8 af[2], kf[2];
        af[0] = *(const bf16x8*)((const char*)QL + (size_t)(wr + r16) * 1024 + slotB);
        af[1] = *(const bf16x8*)((const char*)QL + (size_t)(wr + 16 + r16) * 1024 + slotB);
#pragma unroll
        for (int j = 0; j < 2; ++j) {
          const int row = wcq + j * 16 + r16;
          kf[j] = *(const bf16x8*)((const char*)&Kst[t % 3][0] +
                                   row * 64 + ((q4 ^ ((row >> 1) & 3)) << 4));
        }
        __builtin_amdgcn_s_setprio(1);
#pragma unroll
        for (int i = 0; i < 2; ++i)
#pragma unroll
          for (int j = 0; j < 2; ++j)
            acc_s[i][j] = __builtin_amdgcn_mfma_f32_16x16x32_bf16(af[i], kf[j], acc_s[i][j], 0, 0, 0);
        __builtin_amdgcn_s_setprio(0);
      } else {
        // ---- PV body u = s-16: 8 MFMA ----
        const int u = s - 16;
        const int s4 = u & 3, h = u >> 2;
        bf16x8 pf[2], gf[4];
#pragma unroll
        for (int i = 0; i < 2; ++i) {
          const int row = wr + i * 16 + r16;
          int byteoff = row * 256 + (s4 * 32 + q4 * 8) * 2;
          byteoff ^= (row & 7) << 4;
          pf[i] = *(const bf16x8*)((const char*)Pl + byteoff);
        }
#pragma unroll
        for (int jj = 0; jj < 4; ++jj) {
          const int row = (w & 3) * 64 + jj * 16 + r16;
          gf[jj] = *(const bf16x8*)((const char*)&Gst[u % 3][0] +
                                    row * 64 + ((q4 ^ ((row >> 1) & 3)) << 4));
        }
        __builtin_amdgcn_s_setprio(1);
#pragma unroll
        for (int i = 0; i < 2; ++i)
#pragma unroll
          for (int jj = 0; jj < 4; ++jj)
            acc_o[i][h * 4 + jj] =
                __builtin_amdgcn_mfma_f32_16x16x32_bf16(pf[i], gf[jj], acc_o[i][h * 4 + jj], 0, 0, 0);
        __builtin_amdgcn_s_setprio(0);
      }

      if (s == 15) {
        // ---- softmax epilogue: p = exp(s) (|logits| small -> no max);
        //      P -> Pl swizzled; partial rowsums (disjoint per wave) ----
        float prow[2][4] = {};
#pragma unroll
        for (int i = 0; i < 2; ++i) {
          const int row0 = wr + i * 16 + q4 * 4;
#pragma unroll
          for (int j = 0; j < 2; ++j) {
            const int col = wcq + j * 16 + r16;
#pragma unroll
            for (int r = 0; r < 4; ++r) {
              float p = __expf(acc_s[i][j][r]);
              prow[i][r] += p;
              int byteoff = ((row0 + r) * 128 + col) * 2;
              byteoff ^= ((row0 + r) & 7) << 4;
              *(bf16*)((char*)Pl + byteoff) = (bf16)p;
            }
          }
        }
#pragma unroll
        for (int i = 0; i < 2; ++i)
#pragma unroll
          for (int r = 0; r < 4; ++r) {
            float v = prow[i][r];
            v += __shfl_xor(v, 1);
            v += __shfl_xor(v, 2);
            v += __shfl_xor(v, 4);
            v += __shfl_xor(v, 8);
            if (r16 == 0) rowsum4[w & 3][wr + i * 16 + q4 * 4 + r] += v;
          }
      }
      __builtin_amdgcn_sched_barrier(0);
      __builtin_amdgcn_s_barrier();
    }
  }

  // ---- final: divide by total rowsum, store bf16 ----
#pragma unroll
  for (int i = 0; i < 2; ++i) {
    const int row0 = wr + i * 16 + q4 * 4;
    float inv[4];
#pragma unroll
    for (int r = 0; r < 4; ++r) {
      float rs = rowsum4[0][row0 + r] + rowsum4[1][row0 + r] +
                 rowsum4[2][row0 + r] + rowsum4[3][row0 + r];
      inv[r] = 1.0f / rs;
    }
#pragma unroll
    for (int idx = 0; idx < 8; ++idx) {
      const int col = (idx >> 2) * 256 + (w & 3) * 64 + (idx & 3) * 16 + r16;
#pragma unroll
      for (int r = 0; r < 4; ++r)
        T[(size_t)(row0 + r) * 512 + col] = (bf16)(acc_o[i][idx][r] * inv[r]);
    }
  }
}

// ---------------- launch ----------------
extern "C" void kernel_launch(void* const* d_in, const int* in_sizes, int n_in,
                              void* d_out, int out_size, void* d_ws, size_t ws_size,
                              hipStream_t stream) {
  const float* x  = (const float*)d_in[0];
  const float* Wt = (const float*)d_in[1];
  const float* bt = (const float*)d_in[2];
  const float* Wp = (const float*)d_in[3];
  const float* bp = (const float*)d_in[4];
  const float* Wg = (const float*)d_in[5];
  const float* bg = (const float*)d_in[6];
  const float* Wo = (const float*)d_in[7];
  const float* bo = (const float*)d_in[8];
  float* out = (float*)d_out;

  const size_t MB = 1024ull * 1024ull;
  char* ws = (char*)d_ws;
  bf16* WtB = (bf16*)(ws + 0 * MB);
  bf16* WpB = (bf16*)(ws + 1 * MB);
  bf16* WgB = (bf16*)(ws + 2 * MB);
  bf16* WoB = (bf16*)(ws + 3 * MB);

  cast_f2b<<<512, 256, 0, stream>>>(Wt, WtB, 512 * 1024);
  cast_f2b<<<512, 256, 0, stream>>>(Wp, WpB, 512 * 1024);
  cast_f2b<<<512, 256, 0, stream>>>(Wg, WgB, 512 * 1024);
  cast_f2b<<<512, 256, 0, stream>>>(Wo, WoB, 1024 * 512);

  const float SCALE = 0.044194173824159216f;  // 512^-0.5, folded into theta

  auto run_tail = [&](int nb, int b0, bf16* pxT, bf16* phiT, bf16* g,
                      bf16* thetaT, bf16* tT) {
    gemm_bt<1><<<dim3(8, 4, nb), 256, 0, stream>>>(pxT, 1024ll * 1024, 1024, WpB, 0, 1024,
                                                   phiT, 1024ll * 512, 512, 1024,
                                                   bp, nullptr, 0, 1.f);
    gemm_bt<2><<<dim3(4, 8, nb), 256, 0, stream>>>(WgB, 0, 1024, pxT, 1024ll * 1024, 1024,
                                                   g, 512ll * 1024, 1024, 1024,
                                                   bg, nullptr, 0, 1.f);
    attn_kernel<<<dim3(64, nb), 512, 0, stream>>>(thetaT, phiT, g, tT);
    gemm_bt<4><<<dim3(8, 32, nb), 256, 0, stream>>>(WoB, 0, 512, tT, 4096ll * 512, 512,
                                                    out + (size_t)b0 * 1024 * 4096,
                                                    1024ll * 4096, 4096, 512,
                                                    bo, x + (size_t)b0 * 1024 * 4096,
                                                    1024ll * 4096, 1.f);
  };

  if (ws_size >= 164 * MB) {
    bf16* pxT    = (bf16*)(ws + 4 * MB);     // 16MB
    bf16* phiT   = (bf16*)(ws + 20 * MB);    // 8MB
    bf16* g      = (bf16*)(ws + 28 * MB);    // 8MB
    bf16* thetaT = (bf16*)(ws + 36 * MB);    // 32MB
    bf16* tT     = (bf16*)(ws + 68 * MB);    // 32MB
    bf16* xbT    = (bf16*)(ws + 100 * MB);   // 64MB
    prep_kernel<<<dim3(1024, 8), 256, 0, stream>>>(x, xbT, pxT);
    gemm_bt<1><<<dim3(32, 4, 8), 256, 0, stream>>>(xbT, 4096ll * 1024, 1024, WtB, 0, 1024,
                                                   thetaT, 4096ll * 512, 512, 1024,
                                                   bt, nullptr, 0, SCALE);
    run_tail(8, 0, pxT, phiT, g, thetaT, tT);
  } else if (ws_size >= 108 * MB) {
    bf16* pxT    = (bf16*)(ws + 4 * MB);
    bf16* phiT   = (bf16*)(ws + 20 * MB);
    bf16* g      = (bf16*)(ws + 28 * MB);
    bf16* thetaT = (bf16*)(ws + 36 * MB);
    bf16* tT     = (bf16*)(ws + 68 * MB);
    bf16* xbT    = (bf16*)(ws + 100 * MB);   // 8MB, per-batch
    for (int b = 0; b < 8; ++b) {
      prep_kernel<<<dim3(1024, 1), 256, 0, stream>>>(x + (size_t)b * 1024 * 4096, xbT,
                                                     pxT + (size_t)b * 1024 * 1024);
      gemm_bt<1><<<dim3(32, 4, 1), 256, 0, stream>>>(xbT, 0, 1024, WtB, 0, 1024,
                                                     thetaT + (size_t)b * 4096 * 512, 0, 512,
                                                     1024, bt, nullptr, 0, SCALE);
    }
    run_tail(8, 0, pxT, phiT, g, thetaT, tT);
  } else {
    bf16* pxT    = (bf16*)(ws + 4 * MB);     // 2MB
    bf16* phiT   = (bf16*)(ws + 6 * MB);     // 1MB
    bf16* g      = (bf16*)(ws + 7 * MB);     // 1MB
    bf16* thetaT = (bf16*)(ws + 8 * MB);     // 4MB
    bf16* tT     = (bf16*)(ws + 12 * MB);    // 4MB
    bf16* xbT    = (bf16*)(ws + 16 * MB);    // 8MB
    for (int b = 0; b < 8; ++b) {
      prep_kernel<<<dim3(1024, 1), 256, 0, stream>>>(x + (size_t)b * 1024 * 4096, xbT, pxT);
      gemm_bt<1><<<dim3(32, 4, 1), 256, 0, stream>>>(xbT, 0, 1024, WtB, 0, 1024,
                                                     thetaT, 0, 512, 1024,
                                                     bt, nullptr, 0, SCALE);
      run_tail(1, b, pxT, phiT, g, thetaT, tT);
    }
  }
}

// Round 7
// 356.965 us; speedup vs baseline: 1.4423x; 1.1457x over previous
//
#include <hip/hip_runtime.h>
#include <hip/hip_bf16.h>
#include <stdint.h>

typedef __bf16 bf16;
typedef __bf16 bf16x8 __attribute__((ext_vector_type(8)));
typedef __bf16 bf16x4 __attribute__((ext_vector_type(4)));
typedef float f32x4 __attribute__((ext_vector_type(4)));

#define GLOAD_LDS16(gptr, lptr)                                                        \
  __builtin_amdgcn_global_load_lds((const __attribute__((address_space(1))) void*)(gptr), \
                                   (__attribute__((address_space(3))) void*)(lptr), 16, 0, 0)

// ---------------- weight cast fp32 -> bf16 ----------------
__global__ __launch_bounds__(256) void cast_f2b(const float* __restrict__ in,
                                                bf16* __restrict__ out, int n) {
  int i = (blockIdx.x * 256 + threadIdx.x) * 4;
  if (i >= n) return;
  const float4 v = *(const float4*)(in + i);
  bf16x4 o;
  o[0] = (bf16)v.x; o[1] = (bf16)v.y; o[2] = (bf16)v.z; o[3] = (bf16)v.w;
  *(bf16x4*)(out + i) = o;
}

// ---------------- prep: cast+transpose x -> xbT[n][c], 2x2 maxpool -> pxT[m][c] ----
__global__ __launch_bounds__(256) void prep_kernel(const float* __restrict__ x,
                                                   bf16* __restrict__ xbT,
                                                   bf16* __restrict__ pxT) {
  const int b = blockIdx.y;
  x   += (size_t)b * 1024 * 4096;
  xbT += (size_t)b * 4096 * 1024;
  pxT += (size_t)b * 1024 * 1024;
  const int bid = blockIdx.x;
  const int h0 = bid & 31, ct = bid >> 5;
  const int tid = threadIdx.x;
  __shared__ float tile[32][129];
  const float* xs = x + (size_t)(ct * 32) * 4096 + h0 * 128;
#pragma unroll
  for (int e = 0; e < 16; ++e) {
    int idx = e * 256 + tid;
    int c = idx >> 7, n = idx & 127;
    tile[c][n] = xs[(size_t)c * 4096 + n];
  }
  __syncthreads();
  bf16* xo = xbT + (size_t)(h0 * 128) * 1024 + ct * 32;
#pragma unroll
  for (int e = 0; e < 16; ++e) {
    int idx = e * 256 + tid;
    int n = idx >> 5, c = idx & 31;
    xo[(size_t)n * 1024 + c] = (bf16)tile[c][n];
  }
  bf16* po = pxT + (size_t)(h0 * 32) * 1024 + ct * 32;
#pragma unroll
  for (int e = 0; e < 4; ++e) {
    int idx = e * 256 + tid;
    int m = idx >> 5, c = idx & 31;
    float v = fmaxf(fmaxf(tile[c][2 * m], tile[c][2 * m + 1]),
                    fmaxf(tile[c][64 + 2 * m], tile[c][64 + 2 * m + 1]));
    po[(size_t)m * 1024 + c] = (bf16)v;
  }
}

// ---------------- row sums of P~ (bf16 [nrows][1024]) -> fp32 rs[nrows] ----------
__global__ __launch_bounds__(256) void rowsum_k(const bf16* __restrict__ P,
                                                float* __restrict__ rs) {
  const int row = blockIdx.x * 4 + (threadIdx.x >> 6);
  const int lane = threadIdx.x & 63;
  const bf16* Pr = P + (size_t)row * 1024;
  bf16x8 v0 = *(const bf16x8*)(Pr + lane * 16);
  bf16x8 v1 = *(const bf16x8*)(Pr + lane * 16 + 8);
  float s = 0.f;
#pragma unroll
  for (int e = 0; e < 8; ++e) s += (float)v0[e] + (float)v1[e];
#pragma unroll
  for (int o = 32; o > 0; o >>= 1) s += __shfl_xor(s, o);
  if (lane == 0) rs[row] = s;
}

// ---------------- bt-flavor GEMM: C[MxN] = A[MxK] * B[NxK]^T ----------------
// EPI: 1 bf16 store of (acc + bias[col]) * scale
//      2 bf16 store of (acc + bias[row])
//      4 fp32 store of (acc + bias[row] + resid)
//      5 bf16 store of exp(acc)                      [logits -> unnorm softmax]
//      7 bf16 store of acc / bias[z*4096 + row]      [divide by precomputed rowsum]
template <int EPI>
__global__ __launch_bounds__(256) void gemm_bt(
    const bf16* __restrict__ A, long long sA, int lda,
    const bf16* __restrict__ B, long long sB, int ldb,
    void* __restrict__ Cv, long long sC, int ldc, int K,
    const float* __restrict__ bias,
    const float* __restrict__ resid, long long sResid, float scale) {
  const int z = blockIdx.z;
  A += (size_t)z * sA;
  B += (size_t)z * sB;
  const int tid = threadIdx.x;
  const int w = tid >> 6, lane = tid & 63;
  const int r16 = lane & 15, q4 = lane >> 4;
  const long long tileM = (long long)blockIdx.x * 128;
  const long long tileN = (long long)blockIdx.y * 128;

  __shared__ bf16 As[2][128 * 32];
  __shared__ bf16 Bs[2][128 * 32];

  f32x4 acc[4][4] = {};

  const int srow = tid >> 2;
  const int soff = (tid & 3) * 16;
  const char* Ag0 = (const char*)A + ((size_t)(tileM + srow) * lda) * 2 + soff;
  const char* Bg0 = (const char*)B + ((size_t)(tileN + srow) * ldb) * 2 + soff;
  const size_t arow64 = (size_t)64 * lda * 2;
  const size_t brow64 = (size_t)64 * ldb * 2;

  auto stage = [&](int buf, int k0) {
    const char* a = Ag0 + (size_t)k0 * 2;
    const char* b = Bg0 + (size_t)k0 * 2;
    bf16* al = &As[buf][w * 512];
    bf16* bl = &Bs[buf][w * 512];
    GLOAD_LDS16(a, al);
    GLOAD_LDS16(a + arow64, al + 2048);
    GLOAD_LDS16(b, bl);
    GLOAD_LDS16(b + brow64, bl + 2048);
  };

  const int wr = (w >> 1) * 64, wc = (w & 1) * 64;
  const int nt = K >> 5;
  stage(0, 0);
  __syncthreads();
  int cur = 0;
  for (int t = 0; t < nt; ++t) {
    if (t + 1 < nt) stage(cur ^ 1, (t + 1) * 32);
    bf16x8 af[4], bfv[4];
#pragma unroll
    for (int f = 0; f < 4; ++f) {
      af[f]  = *(const bf16x8*)&As[cur][(wr + f * 16 + r16) * 32 + q4 * 8];
      bfv[f] = *(const bf16x8*)&Bs[cur][(wc + f * 16 + r16) * 32 + q4 * 8];
    }
#pragma unroll
    for (int i = 0; i < 4; ++i)
#pragma unroll
      for (int j = 0; j < 4; ++j)
        acc[i][j] = __builtin_amdgcn_mfma_f32_16x16x32_bf16(af[i], bfv[j], acc[i][j], 0, 0, 0);
    __syncthreads();
    cur ^= 1;
  }

  if constexpr (EPI == 4) {
    float* C = (float*)Cv + (size_t)z * sC;
#pragma unroll
    for (int i = 0; i < 4; ++i) {
      const int row0 = (int)tileM + wr + i * 16 + q4 * 4;
#pragma unroll
      for (int j = 0; j < 4; ++j) {
        const int col = (int)tileN + wc + j * 16 + r16;
#pragma unroll
        for (int r = 0; r < 4; ++r) {
          float v = acc[i][j][r];
          v += bias[row0 + r];
          v += resid[(size_t)z * sResid + (size_t)(row0 + r) * ldc + col];
          C[(size_t)(row0 + r) * ldc + col] = v;
        }
      }
    }
  } else if constexpr (EPI == 5) {
    bf16* C = (bf16*)Cv + (size_t)z * sC;
#pragma unroll
    for (int i = 0; i < 4; ++i) {
      const int row0 = (int)tileM + wr + i * 16 + q4 * 4;
#pragma unroll
      for (int j = 0; j < 4; ++j) {
        const int col = (int)tileN + wc + j * 16 + r16;
#pragma unroll
        for (int r = 0; r < 4; ++r)
          C[(size_t)(row0 + r) * ldc + col] = (bf16)__expf(acc[i][j][r]);
      }
    }
  } else if constexpr (EPI == 7) {
    bf16* C = (bf16*)Cv + (size_t)z * sC;
    const float* rsp = bias + (size_t)z * 4096;
#pragma unroll
    for (int i = 0; i < 4; ++i) {
      const int row0 = (int)tileM + wr + i * 16 + q4 * 4;
      float inv[4];
#pragma unroll
      for (int r = 0; r < 4; ++r) inv[r] = 1.0f / rsp[row0 + r];
#pragma unroll
      for (int j = 0; j < 4; ++j) {
        const int col = (int)tileN + wc + j * 16 + r16;
#pragma unroll
        for (int r = 0; r < 4; ++r)
          C[(size_t)(row0 + r) * ldc + col] = (bf16)(acc[i][j][r] * inv[r]);
      }
    }
  } else {
    bf16* C = (bf16*)Cv + (size_t)z * sC;
#pragma unroll
    for (int i = 0; i < 4; ++i) {
      const int row0 = (int)tileM + wr + i * 16 + q4 * 4;
#pragma unroll
      for (int j = 0; j < 4; ++j) {
        const int col = (int)tileN + wc + j * 16 + r16;
        float badd = 0.f;
        if constexpr (EPI == 1) badd = bias[col];
#pragma unroll
        for (int r = 0; r < 4; ++r) {
          float v = acc[i][j][r];
          if constexpr (EPI == 1) v = (v + badd) * scale;
          if constexpr (EPI == 2) v += bias[row0 + r];
          C[(size_t)(row0 + r) * ldc + col] = (bf16)v;
        }
      }
    }
  }
}

// ---------------- launch ----------------
extern "C" void kernel_launch(void* const* d_in, const int* in_sizes, int n_in,
                              void* d_out, int out_size, void* d_ws, size_t ws_size,
                              hipStream_t stream) {
  const float* x  = (const float*)d_in[0];
  const float* Wt = (const float*)d_in[1];
  const float* bt = (const float*)d_in[2];
  const float* Wp = (const float*)d_in[3];
  const float* bp = (const float*)d_in[4];
  const float* Wg = (const float*)d_in[5];
  const float* bg = (const float*)d_in[6];
  const float* Wo = (const float*)d_in[7];
  const float* bo = (const float*)d_in[8];
  float* out = (float*)d_out;

  const size_t MB = 1024ull * 1024ull;
  char* ws = (char*)d_ws;
  bf16* WtB = (bf16*)(ws + 0 * MB);
  bf16* WpB = (bf16*)(ws + 1 * MB);
  bf16* WgB = (bf16*)(ws + 2 * MB);
  bf16* WoB = (bf16*)(ws + 3 * MB);

  cast_f2b<<<512, 256, 0, stream>>>(Wt, WtB, 512 * 1024);
  cast_f2b<<<512, 256, 0, stream>>>(Wp, WpB, 512 * 1024);
  cast_f2b<<<512, 256, 0, stream>>>(Wg, WgB, 512 * 1024);
  cast_f2b<<<512, 256, 0, stream>>>(Wo, WoB, 1024 * 512);

  const float SCALE = 0.044194173824159216f;  // 512^-0.5, folded into theta

  auto run_g6 = [&](int nb, int b0, bf16* tT) {
    gemm_bt<4><<<dim3(8, 32, nb), 256, 0, stream>>>(WoB, 0, 512, tT, 4096ll * 512, 512,
                                                    out + (size_t)b0 * 1024 * 4096,
                                                    1024ll * 4096, 4096, 512,
                                                    bo, x + (size_t)b0 * 1024 * 4096,
                                                    1024ll * 4096, 1.f);
  };

  if (ws_size >= 164 * MB) {
    bf16* pxT    = (bf16*)(ws + 4 * MB);     // 16MB
    bf16* phiT   = (bf16*)(ws + 20 * MB);    // 8MB
    bf16* g      = (bf16*)(ws + 28 * MB);    // 8MB
    bf16* thetaT = (bf16*)(ws + 36 * MB);    // 32MB
    bf16* tT     = (bf16*)(ws + 68 * MB);    // 32MB
    bf16* xbT    = (bf16*)(ws + 100 * MB);   // 64MB (staging only; no aliasing)
    bf16*  Pt   = (bf16*)d_out;                       // 64MB scratch in d_out
    float* rsum = (float*)((char*)d_out + 80 * MB);   // 128KB scratch in d_out

    prep_kernel<<<dim3(1024, 8), 256, 0, stream>>>(x, xbT, pxT);
    gemm_bt<1><<<dim3(32, 4, 8), 256, 0, stream>>>(xbT, 4096ll * 1024, 1024, WtB, 0, 1024,
                                                   thetaT, 4096ll * 512, 512, 1024,
                                                   bt, nullptr, 0, SCALE);
    gemm_bt<1><<<dim3(8, 4, 8), 256, 0, stream>>>(pxT, 1024ll * 1024, 1024, WpB, 0, 1024,
                                                  phiT, 1024ll * 512, 512, 1024,
                                                  bp, nullptr, 0, 1.f);
    gemm_bt<2><<<dim3(4, 8, 8), 256, 0, stream>>>(WgB, 0, 1024, pxT, 1024ll * 1024, 1024,
                                                  g, 512ll * 1024, 1024, 1024,
                                                  bg, nullptr, 0, 1.f);
    // G4': P~ = exp(theta . phi^T) -> d_out scratch
    gemm_bt<5><<<dim3(32, 8, 8), 256, 0, stream>>>(thetaT, 4096ll * 512, 512,
                                                   phiT, 1024ll * 512, 512,
                                                   Pt, 4096ll * 1024, 1024, 512,
                                                   nullptr, nullptr, 0, 1.f);
    rowsum_k<<<8192, 256, 0, stream>>>(Pt, rsum);
    // G5'': tT = (P~ . g^T) / rowsum
    gemm_bt<7><<<dim3(32, 4, 8), 256, 0, stream>>>(Pt, 4096ll * 1024, 1024,
                                                   g, 512ll * 1024, 1024,
                                                   tT, 4096ll * 512, 512, 1024,
                                                   rsum, nullptr, 0, 1.f);
    run_g6(8, 0, tT);
  } else if (ws_size >= 108 * MB) {
    bf16* pxT    = (bf16*)(ws + 4 * MB);
    bf16* phiT   = (bf16*)(ws + 20 * MB);
    bf16* g      = (bf16*)(ws + 28 * MB);
    bf16* thetaT = (bf16*)(ws + 36 * MB);
    bf16* tT     = (bf16*)(ws + 68 * MB);
    bf16* xbT    = (bf16*)(ws + 100 * MB);   // 8MB per-batch staging
    float* rsum = (float*)((char*)d_out + 80 * MB);
    for (int b = 0; b < 8; ++b) {
      prep_kernel<<<dim3(1024, 1), 256, 0, stream>>>(x + (size_t)b * 1024 * 4096, xbT,
                                                     pxT + (size_t)b * 1024 * 1024);
      gemm_bt<1><<<dim3(32, 4, 1), 256, 0, stream>>>(xbT, 0, 1024, WtB, 0, 1024,
                                                     thetaT + (size_t)b * 4096 * 512, 0, 512,
                                                     1024, bt, nullptr, 0, SCALE);
    }
    gemm_bt<1><<<dim3(8, 4, 8), 256, 0, stream>>>(pxT, 1024ll * 1024, 1024, WpB, 0, 1024,
                                                  phiT, 1024ll * 512, 512, 1024,
                                                  bp, nullptr, 0, 1.f);
    gemm_bt<2><<<dim3(4, 8, 8), 256, 0, stream>>>(WgB, 0, 1024, pxT, 1024ll * 1024, 1024,
                                                  g, 512ll * 1024, 1024, 1024,
                                                  bg, nullptr, 0, 1.f);
    for (int b = 0; b < 8; ++b) {
      bf16* Ptb = (bf16*)d_out + (size_t)b * 4096 * 1024;  // d_out scratch slice
      gemm_bt<5><<<dim3(32, 8, 1), 256, 0, stream>>>(thetaT + (size_t)b * 4096 * 512, 0, 512,
                                                     phiT + (size_t)b * 1024 * 512, 0, 512,
                                                     Ptb, 0, 1024, 512,
                                                     nullptr, nullptr, 0, 1.f);
      rowsum_k<<<1024, 256, 0, stream>>>(Ptb, rsum + (size_t)b * 4096);
      gemm_bt<7><<<dim3(32, 4, 1), 256, 0, stream>>>(Ptb, 0, 1024,
                                                     g + (size_t)b * 512 * 1024, 0, 1024,
                                                     tT + (size_t)b * 4096 * 512, 0, 512, 1024,
                                                     rsum + (size_t)b * 4096, nullptr, 0, 1.f);
    }
    run_g6(8, 0, tT);
  } else {
    // per-batch everything (needs ~34MB); P~ and rsum live in ws (no aliasing)
    float* rsum  = (float*)(ws + 4 * MB);    // 16KB
    bf16* pxT    = (bf16*)(ws + 5 * MB);     // 2MB
    bf16* phiT   = (bf16*)(ws + 7 * MB);     // 1MB
    bf16* g      = (bf16*)(ws + 8 * MB);     // 1MB
    bf16* thetaT = (bf16*)(ws + 9 * MB);     // 4MB
    bf16* tT     = (bf16*)(ws + 13 * MB);    // 4MB
    bf16* Pt     = (bf16*)(ws + 17 * MB);    // 8MB
    bf16* xbT    = (bf16*)(ws + 25 * MB);    // 8MB -> 33MB total
    for (int b = 0; b < 8; ++b) {
      prep_kernel<<<dim3(1024, 1), 256, 0, stream>>>(x + (size_t)b * 1024 * 4096, xbT, pxT);
      gemm_bt<1><<<dim3(32, 4, 1), 256, 0, stream>>>(xbT, 0, 1024, WtB, 0, 1024,
                                                     thetaT, 0, 512, 1024,
                                                     bt, nullptr, 0, SCALE);
      gemm_bt<1><<<dim3(8, 4, 1), 256, 0, stream>>>(pxT, 0, 1024, WpB, 0, 1024,
                                                    phiT, 0, 512, 1024,
                                                    bp, nullptr, 0, 1.f);
      gemm_bt<2><<<dim3(4, 8, 1), 256, 0, stream>>>(WgB, 0, 1024, pxT, 0, 1024,
                                                    g, 0, 1024, 1024,
                                                    bg, nullptr, 0, 1.f);
      gemm_bt<5><<<dim3(32, 8, 1), 256, 0, stream>>>(thetaT, 0, 512, phiT, 0, 512,
                                                     Pt, 0, 1024, 512,
                                                     nullptr, nullptr, 0, 1.f);
      rowsum_k<<<1024, 256, 0, stream>>>(Pt, rsum);
      gemm_bt<7><<<dim3(32, 4, 1), 256, 0, stream>>>(Pt, 0, 1024, g, 0, 1024,
                                                     tT, 0, 512, 1024,
                                                     rsum, nullptr, 0, 1.f);
      run_g6(1, b, tT);
    }
  }
}

// Round 8
// 322.900 us; speedup vs baseline: 1.5945x; 1.1055x over previous
//
#include <hip/hip_runtime.h>
#include <hip/hip_bf16.h>
#include <stdint.h>

typedef __bf16 bf16;
typedef __bf16 bf16x8 __attribute__((ext_vector_type(8)));
typedef __bf16 bf16x4 __attribute__((ext_vector_type(4)));
typedef float f32x4 __attribute__((ext_vector_type(4)));

#define GLOAD_LDS16(gptr, lptr)                                                        \
  __builtin_amdgcn_global_load_lds((const __attribute__((address_space(1))) void*)(gptr), \
                                   (__attribute__((address_space(3))) void*)(lptr), 16, 0, 0)

// ---------------- weight cast fp32 -> bf16 ----------------
__global__ __launch_bounds__(256) void cast_f2b(const float* __restrict__ in,
                                                bf16* __restrict__ out, int n) {
  int i = (blockIdx.x * 256 + threadIdx.x) * 4;
  if (i >= n) return;
  const float4 v = *(const float4*)(in + i);
  bf16x4 o;
  o[0] = (bf16)v.x; o[1] = (bf16)v.y; o[2] = (bf16)v.z; o[3] = (bf16)v.w;
  *(bf16x4*)(out + i) = o;
}

// ---------------- prep: cast+transpose x -> xbT[n][c], 2x2 maxpool -> pxT[m][c] ----
__global__ __launch_bounds__(256) void prep_kernel(const float* __restrict__ x,
                                                   bf16* __restrict__ xbT,
                                                   bf16* __restrict__ pxT) {
  const int b = blockIdx.y;
  x   += (size_t)b * 1024 * 4096;
  xbT += (size_t)b * 4096 * 1024;
  pxT += (size_t)b * 1024 * 1024;
  const int bid = blockIdx.x;
  const int h0 = bid & 31, ct = bid >> 5;
  const int tid = threadIdx.x;
  __shared__ float tile[32][129];
  const float* xs = x + (size_t)(ct * 32) * 4096 + h0 * 128;
#pragma unroll
  for (int e = 0; e < 16; ++e) {
    int idx = e * 256 + tid;
    int c = idx >> 7, n = idx & 127;
    tile[c][n] = xs[(size_t)c * 4096 + n];
  }
  __syncthreads();
  bf16* xo = xbT + (size_t)(h0 * 128) * 1024 + ct * 32;
#pragma unroll
  for (int e = 0; e < 16; ++e) {
    int idx = e * 256 + tid;
    int n = idx >> 5, c = idx & 31;
    xo[(size_t)n * 1024 + c] = (bf16)tile[c][n];
  }
  bf16* po = pxT + (size_t)(h0 * 32) * 1024 + ct * 32;
#pragma unroll
  for (int e = 0; e < 4; ++e) {
    int idx = e * 256 + tid;
    int m = idx >> 5, c = idx & 31;
    float v = fmaxf(fmaxf(tile[c][2 * m], tile[c][2 * m + 1]),
                    fmaxf(tile[c][64 + 2 * m], tile[c][64 + 2 * m + 1]));
    po[(size_t)m * 1024 + c] = (bf16)v;
  }
}

// ---------------- row sums of P~ (bf16 [nrows][1024]) -> fp32 rs[nrows] ----------
__global__ __launch_bounds__(256) void rowsum_k(const bf16* __restrict__ P,
                                                float* __restrict__ rs) {
  const int row = blockIdx.x * 4 + (threadIdx.x >> 6);
  const int lane = threadIdx.x & 63;
  const bf16* Pr = P + (size_t)row * 1024;
  bf16x8 v0 = *(const bf16x8*)(Pr + lane * 16);
  bf16x8 v1 = *(const bf16x8*)(Pr + lane * 16 + 8);
  float s = 0.f;
#pragma unroll
  for (int e = 0; e < 8; ++e) s += (float)v0[e] + (float)v1[e];
#pragma unroll
  for (int o = 32; o > 0; o >>= 1) s += __shfl_xor(s, o);
  if (lane == 0) rs[row] = s;
}

// ======== 256x256-tile counted-vmcnt GEMM: C[MxN] = A[MxK] * B[NxK]^T ========
// 8 waves (2M x 4N), per-wave 128x64 output. BK=32, ring-4 LDS slots.
// Per K-tile T: issue stage(T+2).A, vmcnt(6|4|0), s_barrier, swizzled ds_reads
// + 32 MFMA (issue stage(T+2).B mid-tile). Slot T%4 read vs slot (T+2)%4
// written => race-free for any <1-tile wave drift (bounded by the barrier).
// LDS swizzle: 16B slot s = kb ^ ((row>>1)&3), inverse applied on global src.
// EPI: 1 bf16 (acc+bias[col])*scale ; 4 fp32 acc+bias[row]+resid ;
//      5 bf16 exp(acc) ; 7 bf16 acc / bias[z*4096+row]
template <int EPI>
__global__ __launch_bounds__(512, 1) void gemm256(
    const bf16* __restrict__ A, long long sA, int lda,
    const bf16* __restrict__ B, long long sB, int ldb,
    void* __restrict__ Cv, long long sC, int ldc, int K,
    const float* __restrict__ bias,
    const float* __restrict__ resid, long long sResid, float scale) {
  const int z = blockIdx.z;
  A += (size_t)z * sA;
  B += (size_t)z * sB;
  const int tid = threadIdx.x;
  const int w = tid >> 6, lane = tid & 63;
  const int r16 = lane & 15, q4 = lane >> 4;
  const int wm = w >> 2, wn = w & 3;
  const long long tileM = (long long)blockIdx.x * 256;
  const long long tileN = (long long)blockIdx.y * 256;

  __shared__ bf16 As[4][8192];  // 64KB: [slot][256 rows][32 k], swizzled 16B lanes
  __shared__ bf16 Bs[4][8192];  // 64KB

  f32x4 acc[8][4] = {};

  // staging: lane covers (row = tid>>2 (+128 for half1), 16B-slot = tid&3)
  const int srow = tid >> 2;
  const int skb  = (tid & 3) ^ ((srow >> 1) & 3);   // inverse swizzle on source
  const char* Ag = (const char*)A + ((size_t)(tileM + srow) * lda + skb * 8) * 2;
  const char* Bg = (const char*)B + ((size_t)(tileN + srow) * ldb + skb * 8) * 2;
  const size_t a128 = (size_t)128 * lda * 2;
  const size_t b128 = (size_t)128 * ldb * 2;

  auto stA = [&](int T) {  // 2 vm-ops
    bf16* d = &As[T & 3][w * 512];
    const char* s = Ag + (size_t)T * 64;
    GLOAD_LDS16(s, d);
    GLOAD_LDS16(s + a128, d + 4096);
  };
  auto stB = [&](int T) {  // 2 vm-ops
    bf16* d = &Bs[T & 3][w * 512];
    const char* s = Bg + (size_t)T * 64;
    GLOAD_LDS16(s, d);
    GLOAD_LDS16(s + b128, d + 4096);
  };

  stA(0); stB(0); stA(1); stB(1);
  const int NT = K >> 5;

  for (int T = 0; T < NT; ++T) {
    if (T + 2 < NT) stA(T + 2);
    // outstanding newer-than-T after this issue: (T+1)<NT -> 4 ops, (T+2)<NT -> +2
    if (T + 2 < NT)      asm volatile("s_waitcnt vmcnt(6)" ::: "memory");
    else if (T + 1 < NT) asm volatile("s_waitcnt vmcnt(4)" ::: "memory");
    else                 asm volatile("s_waitcnt vmcnt(0)" ::: "memory");
    __builtin_amdgcn_s_barrier();
    asm volatile("" ::: "memory");

    const char* Asl = (const char*)&As[T & 3][0];
    const char* Bsl = (const char*)&Bs[T & 3][0];
    bf16x8 bf_[4];
#pragma unroll
    for (int ni = 0; ni < 4; ++ni) {
      const int row = wn * 64 + ni * 16 + r16;
      bf_[ni] = *(const bf16x8*)(Bsl + row * 64 + ((q4 ^ ((row >> 1) & 3)) << 4));
    }
    bf16x8 af[4];
#pragma unroll
    for (int mi = 0; mi < 4; ++mi) {
      const int row = wm * 128 + mi * 16 + r16;
      af[mi] = *(const bf16x8*)(Asl + row * 64 + ((q4 ^ ((row >> 1) & 3)) << 4));
    }
    __builtin_amdgcn_s_setprio(1);
#pragma unroll
    for (int mi = 0; mi < 4; ++mi)
#pragma unroll
      for (int ni = 0; ni < 4; ++ni)
        acc[mi][ni] = __builtin_amdgcn_mfma_f32_16x16x32_bf16(af[mi], bf_[ni], acc[mi][ni], 0, 0, 0);
    __builtin_amdgcn_s_setprio(0);

    if (T + 2 < NT) stB(T + 2);
#pragma unroll
    for (int mi = 0; mi < 4; ++mi) {
      const int row = wm * 128 + 64 + mi * 16 + r16;
      af[mi] = *(const bf16x8*)(Asl + row * 64 + ((q4 ^ ((row >> 1) & 3)) << 4));
    }
    __builtin_amdgcn_s_setprio(1);
#pragma unroll
    for (int mi = 0; mi < 4; ++mi)
#pragma unroll
      for (int ni = 0; ni < 4; ++ni)
        acc[4 + mi][ni] = __builtin_amdgcn_mfma_f32_16x16x32_bf16(af[mi], bf_[ni], acc[4 + mi][ni], 0, 0, 0);
    __builtin_amdgcn_s_setprio(0);
  }

  if constexpr (EPI == 4) {
    float* C = (float*)Cv + (size_t)z * sC;
    const float* rz = resid + (size_t)z * sResid;
#pragma unroll
    for (int a = 0; a < 8; ++a) {
      const int row0 = (int)tileM + wm * 128 + a * 16 + q4 * 4;
#pragma unroll
      for (int ni = 0; ni < 4; ++ni) {
        const int col = (int)tileN + wn * 64 + ni * 16 + r16;
#pragma unroll
        for (int r = 0; r < 4; ++r)
          C[(size_t)(row0 + r) * ldc + col] =
              acc[a][ni][r] + bias[row0 + r] + rz[(size_t)(row0 + r) * ldc + col];
      }
    }
  } else if constexpr (EPI == 5) {
    bf16* C = (bf16*)Cv + (size_t)z * sC;
#pragma unroll
    for (int a = 0; a < 8; ++a) {
      const int row0 = (int)tileM + wm * 128 + a * 16 + q4 * 4;
#pragma unroll
      for (int ni = 0; ni < 4; ++ni) {
        const int col = (int)tileN + wn * 64 + ni * 16 + r16;
#pragma unroll
        for (int r = 0; r < 4; ++r)
          C[(size_t)(row0 + r) * ldc + col] = (bf16)__expf(acc[a][ni][r]);
      }
    }
  } else if constexpr (EPI == 7) {
    bf16* C = (bf16*)Cv + (size_t)z * sC;
    const float* rsp = bias + (size_t)z * 4096;
#pragma unroll
    for (int a = 0; a < 8; ++a) {
      const int row0 = (int)tileM + wm * 128 + a * 16 + q4 * 4;
      float inv[4];
#pragma unroll
      for (int r = 0; r < 4; ++r) inv[r] = 1.0f / rsp[row0 + r];
#pragma unroll
      for (int ni = 0; ni < 4; ++ni) {
        const int col = (int)tileN + wn * 64 + ni * 16 + r16;
#pragma unroll
        for (int r = 0; r < 4; ++r)
          C[(size_t)(row0 + r) * ldc + col] = (bf16)(acc[a][ni][r] * inv[r]);
      }
    }
  } else {  // EPI == 1
    bf16* C = (bf16*)Cv + (size_t)z * sC;
#pragma unroll
    for (int a = 0; a < 8; ++a) {
      const int row0 = (int)tileM + wm * 128 + a * 16 + q4 * 4;
#pragma unroll
      for (int ni = 0; ni < 4; ++ni) {
        const int col = (int)tileN + wn * 64 + ni * 16 + r16;
        const float badd = bias[col];
#pragma unroll
        for (int r = 0; r < 4; ++r)
          C[(size_t)(row0 + r) * ldc + col] = (bf16)((acc[a][ni][r] + badd) * scale);
      }
    }
  }
}

// ---------------- 128^2 bt-GEMM (kept for small shapes G2/G3) ----------------
// EPI: 1 bf16 (acc + bias[col]) * scale; 2 bf16 + bias[row]
template <int EPI>
__global__ __launch_bounds__(256) void gemm_bt(
    const bf16* __restrict__ A, long long sA, int lda,
    const bf16* __restrict__ B, long long sB, int ldb,
    void* __restrict__ Cv, long long sC, int ldc, int K,
    const float* __restrict__ bias,
    const float* __restrict__ resid, long long sResid, float scale) {
  const int z = blockIdx.z;
  A += (size_t)z * sA;
  B += (size_t)z * sB;
  const int tid = threadIdx.x;
  const int w = tid >> 6, lane = tid & 63;
  const int r16 = lane & 15, q4 = lane >> 4;
  const long long tileM = (long long)blockIdx.x * 128;
  const long long tileN = (long long)blockIdx.y * 128;

  __shared__ bf16 As[2][128 * 32];
  __shared__ bf16 Bs[2][128 * 32];

  f32x4 acc[4][4] = {};

  const int srow = tid >> 2;
  const int soff = (tid & 3) * 16;
  const char* Ag0 = (const char*)A + ((size_t)(tileM + srow) * lda) * 2 + soff;
  const char* Bg0 = (const char*)B + ((size_t)(tileN + srow) * ldb) * 2 + soff;
  const size_t arow64 = (size_t)64 * lda * 2;
  const size_t brow64 = (size_t)64 * ldb * 2;

  auto stage = [&](int buf, int k0) {
    const char* a = Ag0 + (size_t)k0 * 2;
    const char* b = Bg0 + (size_t)k0 * 2;
    bf16* al = &As[buf][w * 512];
    bf16* bl = &Bs[buf][w * 512];
    GLOAD_LDS16(a, al);
    GLOAD_LDS16(a + arow64, al + 2048);
    GLOAD_LDS16(b, bl);
    GLOAD_LDS16(b + brow64, bl + 2048);
  };

  const int wr = (w >> 1) * 64, wc = (w & 1) * 64;
  const int nt = K >> 5;
  stage(0, 0);
  __syncthreads();
  int cur = 0;
  for (int t = 0; t < nt; ++t) {
    if (t + 1 < nt) stage(cur ^ 1, (t + 1) * 32);
    bf16x8 af[4], bfv[4];
#pragma unroll
    for (int f = 0; f < 4; ++f) {
      af[f]  = *(const bf16x8*)&As[cur][(wr + f * 16 + r16) * 32 + q4 * 8];
      bfv[f] = *(const bf16x8*)&Bs[cur][(wc + f * 16 + r16) * 32 + q4 * 8];
    }
#pragma unroll
    for (int i = 0; i < 4; ++i)
#pragma unroll
      for (int j = 0; j < 4; ++j)
        acc[i][j] = __builtin_amdgcn_mfma_f32_16x16x32_bf16(af[i], bfv[j], acc[i][j], 0, 0, 0);
    __syncthreads();
    cur ^= 1;
  }

  bf16* C = (bf16*)Cv + (size_t)z * sC;
#pragma unroll
  for (int i = 0; i < 4; ++i) {
    const int row0 = (int)tileM + wr + i * 16 + q4 * 4;
#pragma unroll
    for (int j = 0; j < 4; ++j) {
      const int col = (int)tileN + wc + j * 16 + r16;
      float badd = 0.f;
      if constexpr (EPI == 1) badd = bias[col];
#pragma unroll
      for (int r = 0; r < 4; ++r) {
        float v = acc[i][j][r];
        if constexpr (EPI == 1) v = (v + badd) * scale;
        if constexpr (EPI == 2) v += bias[row0 + r];
        C[(size_t)(row0 + r) * ldc + col] = (bf16)v;
      }
    }
  }
}

// ---------------- launch ----------------
extern "C" void kernel_launch(void* const* d_in, const int* in_sizes, int n_in,
                              void* d_out, int out_size, void* d_ws, size_t ws_size,
                              hipStream_t stream) {
  const float* x  = (const float*)d_in[0];
  const float* Wt = (const float*)d_in[1];
  const float* bt = (const float*)d_in[2];
  const float* Wp = (const float*)d_in[3];
  const float* bp = (const float*)d_in[4];
  const float* Wg = (const float*)d_in[5];
  const float* bg = (const float*)d_in[6];
  const float* Wo = (const float*)d_in[7];
  const float* bo = (const float*)d_in[8];
  float* out = (float*)d_out;

  const size_t MB = 1024ull * 1024ull;
  char* ws = (char*)d_ws;
  bf16* WtB = (bf16*)(ws + 0 * MB);
  bf16* WpB = (bf16*)(ws + 1 * MB);
  bf16* WgB = (bf16*)(ws + 2 * MB);
  bf16* WoB = (bf16*)(ws + 3 * MB);

  cast_f2b<<<512, 256, 0, stream>>>(Wt, WtB, 512 * 1024);
  cast_f2b<<<512, 256, 0, stream>>>(Wp, WpB, 512 * 1024);
  cast_f2b<<<512, 256, 0, stream>>>(Wg, WgB, 512 * 1024);
  cast_f2b<<<512, 256, 0, stream>>>(Wo, WoB, 1024 * 512);

  const float SCALE = 0.044194173824159216f;  // 512^-0.5, folded into theta

  auto run_g6 = [&](int nb, int b0, bf16* tT) {
    gemm256<4><<<dim3(4, 16, nb), 512, 0, stream>>>(WoB, 0, 512, tT, 4096ll * 512, 512,
                                                    out + (size_t)b0 * 1024 * 4096,
                                                    1024ll * 4096, 4096, 512,
                                                    bo, x + (size_t)b0 * 1024 * 4096,
                                                    1024ll * 4096, 1.f);
  };

  if (ws_size >= 164 * MB) {
    bf16* pxT    = (bf16*)(ws + 4 * MB);     // 16MB
    bf16* phiT   = (bf16*)(ws + 20 * MB);    // 8MB
    bf16* g      = (bf16*)(ws + 28 * MB);    // 8MB
    bf16* thetaT = (bf16*)(ws + 36 * MB);    // 32MB
    bf16* tT     = (bf16*)(ws + 68 * MB);    // 32MB
    bf16* xbT    = (bf16*)(ws + 100 * MB);   // 64MB (staging only; no aliasing)
    bf16*  Pt   = (bf16*)d_out;                       // 64MB scratch in d_out
    float* rsum = (float*)((char*)d_out + 80 * MB);   // 128KB scratch in d_out

    prep_kernel<<<dim3(1024, 8), 256, 0, stream>>>(x, xbT, pxT);
    gemm256<1><<<dim3(16, 2, 8), 512, 0, stream>>>(xbT, 4096ll * 1024, 1024, WtB, 0, 1024,
                                                   thetaT, 4096ll * 512, 512, 1024,
                                                   bt, nullptr, 0, SCALE);
    gemm_bt<1><<<dim3(8, 4, 8), 256, 0, stream>>>(pxT, 1024ll * 1024, 1024, WpB, 0, 1024,
                                                  phiT, 1024ll * 512, 512, 1024,
                                                  bp, nullptr, 0, 1.f);
    gemm_bt<2><<<dim3(4, 8, 8), 256, 0, stream>>>(WgB, 0, 1024, pxT, 1024ll * 1024, 1024,
                                                  g, 512ll * 1024, 1024, 1024,
                                                  bg, nullptr, 0, 1.f);
    gemm256<5><<<dim3(16, 4, 8), 512, 0, stream>>>(thetaT, 4096ll * 512, 512,
                                                   phiT, 1024ll * 512, 512,
                                                   Pt, 4096ll * 1024, 1024, 512,
                                                   nullptr, nullptr, 0, 1.f);
    rowsum_k<<<8192, 256, 0, stream>>>(Pt, rsum);
    gemm256<7><<<dim3(16, 2, 8), 512, 0, stream>>>(Pt, 4096ll * 1024, 1024,
                                                   g, 512ll * 1024, 1024,
                                                   tT, 4096ll * 512, 512, 1024,
                                                   rsum, nullptr, 0, 1.f);
    run_g6(8, 0, tT);
  } else if (ws_size >= 108 * MB) {
    bf16* pxT    = (bf16*)(ws + 4 * MB);
    bf16* phiT   = (bf16*)(ws + 20 * MB);
    bf16* g      = (bf16*)(ws + 28 * MB);
    bf16* thetaT = (bf16*)(ws + 36 * MB);
    bf16* tT     = (bf16*)(ws + 68 * MB);
    bf16* xbT    = (bf16*)(ws + 100 * MB);   // 8MB per-batch staging
    float* rsum = (float*)((char*)d_out + 80 * MB);
    for (int b = 0; b < 8; ++b) {
      prep_kernel<<<dim3(1024, 1), 256, 0, stream>>>(x + (size_t)b * 1024 * 4096, xbT,
                                                     pxT + (size_t)b * 1024 * 1024);
      gemm256<1><<<dim3(16, 2, 1), 512, 0, stream>>>(xbT, 0, 1024, WtB, 0, 1024,
                                                     thetaT + (size_t)b * 4096 * 512, 0, 512,
                                                     1024, bt, nullptr, 0, SCALE);
    }
    gemm_bt<1><<<dim3(8, 4, 8), 256, 0, stream>>>(pxT, 1024ll * 1024, 1024, WpB, 0, 1024,
                                                  phiT, 1024ll * 512, 512, 1024,
                                                  bp, nullptr, 0, 1.f);
    gemm_bt<2><<<dim3(4, 8, 8), 256, 0, stream>>>(WgB, 0, 1024, pxT, 1024ll * 1024, 1024,
                                                  g, 512ll * 1024, 1024, 1024,
                                                  bg, nullptr, 0, 1.f);
    for (int b = 0; b < 8; ++b) {
      bf16* Ptb = (bf16*)d_out + (size_t)b * 4096 * 1024;
      gemm256<5><<<dim3(16, 4, 1), 512, 0, stream>>>(thetaT + (size_t)b * 4096 * 512, 0, 512,
                                                     phiT + (size_t)b * 1024 * 512, 0, 512,
                                                     Ptb, 0, 1024, 512,
                                                     nullptr, nullptr, 0, 1.f);
      rowsum_k<<<1024, 256, 0, stream>>>(Ptb, rsum + (size_t)b * 4096);
      gemm256<7><<<dim3(16, 2, 1), 512, 0, stream>>>(Ptb, 0, 1024,
                                                     g + (size_t)b * 512 * 1024, 0, 1024,
                                                     tT + (size_t)b * 4096 * 512, 0, 512, 1024,
                                                     rsum + (size_t)b * 4096, nullptr, 0, 1.f);
    }
    run_g6(8, 0, tT);
  } else {
    float* rsum  = (float*)(ws + 4 * MB);    // 16KB
    bf16* pxT    = (bf16*)(ws + 5 * MB);     // 2MB
    bf16* phiT   = (bf16*)(ws + 7 * MB);     // 1MB
    bf16* g      = (bf16*)(ws + 8 * MB);     // 1MB
    bf16* thetaT = (bf16*)(ws + 9 * MB);     // 4MB
    bf16* tT     = (bf16*)(ws + 13 * MB);    // 4MB
    bf16* Pt     = (bf16*)(ws + 17 * MB);    // 8MB
    bf16* xbT    = (bf16*)(ws + 25 * MB);    // 8MB -> 33MB total
    for (int b = 0; b < 8; ++b) {
      prep_kernel<<<dim3(1024, 1), 256, 0, stream>>>(x + (size_t)b * 1024 * 4096, xbT, pxT);
      gemm256<1><<<dim3(16, 2, 1), 512, 0, stream>>>(xbT, 0, 1024, WtB, 0, 1024,
                                                     thetaT, 0, 512, 1024,
                                                     bt, nullptr, 0, SCALE);
      gemm_bt<1><<<dim3(8, 4, 1), 256, 0, stream>>>(pxT, 0, 1024, WpB, 0, 1024,
                                                    phiT, 0, 512, 1024,
                                                    bp, nullptr, 0, 1.f);
      gemm_bt<2><<<dim3(4, 8, 1), 256, 0, stream>>>(WgB, 0, 1024, pxT, 0, 1024,
                                                    g, 0, 1024, 1024,
                                                    bg, nullptr, 0, 1.f);
      gemm256<5><<<dim3(16, 4, 1), 512, 0, stream>>>(thetaT, 0, 512, phiT, 0, 512,
                                                     Pt, 0, 1024, 512,
                                                     nullptr, nullptr, 0, 1.f);
      rowsum_k<<<1024, 256, 0, stream>>>(Pt, rsum);
      gemm256<7><<<dim3(16, 2, 1), 512, 0, stream>>>(Pt, 0, 1024, g, 0, 1024,
                                                     tT, 0, 512, 1024,
                                                     rsum, nullptr, 0, 1.f);
      run_g6(1, b, tT);
    }
  }
}

// Round 9
// 318.436 us; speedup vs baseline: 1.6168x; 1.0140x over previous
//
#include <hip/hip_runtime.h>
#include <hip/hip_bf16.h>
#include <stdint.h>

typedef __bf16 bf16;
typedef __bf16 bf16x8 __attribute__((ext_vector_type(8)));
typedef __bf16 bf16x4 __attribute__((ext_vector_type(4)));
typedef float f32x4 __attribute__((ext_vector_type(4)));

#define GLOAD_LDS16(gptr, lptr)                                                        \
  __builtin_amdgcn_global_load_lds((const __attribute__((address_space(1))) void*)(gptr), \
                                   (__attribute__((address_space(3))) void*)(lptr), 16, 0, 0)

// ---------------- weight cast fp32 -> bf16 ----------------
__global__ __launch_bounds__(256) void cast_f2b(const float* __restrict__ in,
                                                bf16* __restrict__ out, int n) {
  int i = (blockIdx.x * 256 + threadIdx.x) * 4;
  if (i >= n) return;
  const float4 v = *(const float4*)(in + i);
  bf16x4 o;
  o[0] = (bf16)v.x; o[1] = (bf16)v.y; o[2] = (bf16)v.z; o[3] = (bf16)v.w;
  *(bf16x4*)(out + i) = o;
}

__global__ __launch_bounds__(256) void zero_k(float* __restrict__ p, int n) {
  int i = blockIdx.x * 256 + threadIdx.x;
  if (i < n) p[i] = 0.f;
}

// ---------------- prep: cast+transpose x -> xbT[n][c], 2x2 maxpool -> pxT[m][c] ----
__global__ __launch_bounds__(256) void prep_kernel(const float* __restrict__ x,
                                                   bf16* __restrict__ xbT,
                                                   bf16* __restrict__ pxT) {
  const int b = blockIdx.y;
  x   += (size_t)b * 1024 * 4096;
  xbT += (size_t)b * 4096 * 1024;
  pxT += (size_t)b * 1024 * 1024;
  const int bid = blockIdx.x;
  const int h0 = bid & 31, ct = bid >> 5;
  const int tid = threadIdx.x;
  __shared__ float tile[32][129];
  const float* xs = x + (size_t)(ct * 32) * 4096 + h0 * 128;
#pragma unroll
  for (int e = 0; e < 16; ++e) {
    int idx = e * 256 + tid;
    int c = idx >> 7, n = idx & 127;
    tile[c][n] = xs[(size_t)c * 4096 + n];
  }
  __syncthreads();
  bf16* xo = xbT + (size_t)(h0 * 128) * 1024 + ct * 32;
#pragma unroll
  for (int e = 0; e < 16; ++e) {
    int idx = e * 256 + tid;
    int n = idx >> 5, c = idx & 31;
    xo[(size_t)n * 1024 + c] = (bf16)tile[c][n];
  }
  bf16* po = pxT + (size_t)(h0 * 32) * 1024 + ct * 32;
#pragma unroll
  for (int e = 0; e < 4; ++e) {
    int idx = e * 256 + tid;
    int m = idx >> 5, c = idx & 31;
    float v = fmaxf(fmaxf(tile[c][2 * m], tile[c][2 * m + 1]),
                    fmaxf(tile[c][64 + 2 * m], tile[c][64 + 2 * m + 1]));
    po[(size_t)m * 1024 + c] = (bf16)v;
  }
}

// ======== 128x256-tile GEMM: C[MxN] = A[MxK] * B[NxK]^T ========
// 8 waves (2M x 4N), per-wave 64x64 output. BK=32, ring-2 LDS (48KB -> 2 blk/CU).
// Body T: vmcnt(0) [stage T, 1-deep prefetch] -> s_barrier -> issue stage(T+1)
// -> 8 swizzled ds_read_b128 + 16 MFMA. Write/read hazards separated by the
// barrier (readers' ds_reads drained by compiler lgkm-waits pre-MFMA).
// LDS swizzle: 16B slot = kb ^ ((row>>1)&3), inverse applied on global src.
// EPI: 1 bf16 (acc+bias[col])*scale ; 4 fp32 acc+bias[row]+resid ;
//      5 bf16 exp(acc) + atomic row-sums into rs_out ; 7 bf16 acc/bias[z*4096+row]
template <int EPI>
__global__ __launch_bounds__(512, 4) void gemm256(
    const bf16* __restrict__ A, long long sA, int lda,
    const bf16* __restrict__ B, long long sB, int ldb,
    void* __restrict__ Cv, long long sC, int ldc, int K,
    const float* __restrict__ bias,
    const float* __restrict__ resid, long long sResid, float scale,
    float* __restrict__ rs_out) {
  const int z = blockIdx.z;
  A += (size_t)z * sA;
  B += (size_t)z * sB;
  const int tid = threadIdx.x;
  const int w = tid >> 6, lane = tid & 63;
  const int r16 = lane & 15, q4 = lane >> 4;
  const int wm = w >> 2, wn = w & 3;
  const long long tileM = (long long)blockIdx.x * 128;
  const long long tileN = (long long)blockIdx.y * 256;

  __shared__ bf16 As[2][4096];  // 16KB: [slot][128 rows][32 k], swizzled 16B lanes
  __shared__ bf16 Bs[2][8192];  // 32KB: [slot][256 rows][32 k]

  f32x4 acc[4][4] = {};

  // staging: thread covers (row = tid>>2, 16B-slot = tid&3); B adds row+128.
  const int srow = tid >> 2;
  const int skb  = (tid & 3) ^ ((srow >> 1) & 3);   // inverse swizzle on source
  const char* Ag = (const char*)A + ((size_t)(tileM + srow) * lda + skb * 8) * 2;
  const char* Bg = (const char*)B + ((size_t)(tileN + srow) * ldb + skb * 8) * 2;
  const size_t b128 = (size_t)128 * ldb * 2;   // ((r+128)>>1)&3 == (r>>1)&3

  auto stage = [&](int T) {  // 3 vm-ops
    const int sl = T & 1;
    GLOAD_LDS16(Ag + (size_t)T * 64, &As[sl][w * 512]);
    GLOAD_LDS16(Bg + (size_t)T * 64, &Bs[sl][w * 512]);
    GLOAD_LDS16(Bg + (size_t)T * 64 + b128, &Bs[sl][4096 + w * 512]);
  };

  stage(0);
  const int NT = K >> 5;

  for (int T = 0; T < NT; ++T) {
    asm volatile("s_waitcnt vmcnt(0)" ::: "memory");  // stage(T) done (own ops)
    __builtin_amdgcn_s_barrier();                     // -> all waves' stage(T) done
    asm volatile("" ::: "memory");
    if (T + 1 < NT) stage(T + 1);                     // slot (T+1)&1: old readers
                                                      // finished before this barrier
    const char* Asl = (const char*)&As[T & 1][0];
    const char* Bsl = (const char*)&Bs[T & 1][0];
    bf16x8 af[4], bf_[4];
#pragma unroll
    for (int mi = 0; mi < 4; ++mi) {
      const int row = wm * 64 + mi * 16 + r16;
      af[mi] = *(const bf16x8*)(Asl + row * 64 + ((q4 ^ ((row >> 1) & 3)) << 4));
    }
#pragma unroll
    for (int ni = 0; ni < 4; ++ni) {
      const int row = wn * 64 + ni * 16 + r16;
      bf_[ni] = *(const bf16x8*)(Bsl + row * 64 + ((q4 ^ ((row >> 1) & 3)) << 4));
    }
    __builtin_amdgcn_s_setprio(1);
#pragma unroll
    for (int mi = 0; mi < 4; ++mi)
#pragma unroll
      for (int ni = 0; ni < 4; ++ni)
        acc[mi][ni] = __builtin_amdgcn_mfma_f32_16x16x32_bf16(af[mi], bf_[ni], acc[mi][ni], 0, 0, 0);
    __builtin_amdgcn_s_setprio(0);
  }

  if constexpr (EPI == 4) {
    float* C = (float*)Cv + (size_t)z * sC;
    const float* rz = resid + (size_t)z * sResid;
#pragma unroll
    for (int a = 0; a < 4; ++a) {
      const int row0 = (int)tileM + wm * 64 + a * 16 + q4 * 4;
#pragma unroll
      for (int ni = 0; ni < 4; ++ni) {
        const int col = (int)tileN + wn * 64 + ni * 16 + r16;
#pragma unroll
        for (int r = 0; r < 4; ++r)
          C[(size_t)(row0 + r) * ldc + col] =
              acc[a][ni][r] + bias[row0 + r] + rz[(size_t)(row0 + r) * ldc + col];
      }
    }
  } else if constexpr (EPI == 5) {
    bf16* C = (bf16*)Cv + (size_t)z * sC;
    float* rsp = rs_out + (size_t)z * 4096;
#pragma unroll
    for (int a = 0; a < 4; ++a) {
      const int row0 = (int)tileM + wm * 64 + a * 16 + q4 * 4;
      float psum[4] = {0.f, 0.f, 0.f, 0.f};
#pragma unroll
      for (int ni = 0; ni < 4; ++ni) {
        const int col = (int)tileN + wn * 64 + ni * 16 + r16;
#pragma unroll
        for (int r = 0; r < 4; ++r) {
          float e = __expf(acc[a][ni][r]);
          psum[r] += e;
          C[(size_t)(row0 + r) * ldc + col] = (bf16)e;
        }
      }
#pragma unroll
      for (int r = 0; r < 4; ++r) {
        float v = psum[r];
        v += __shfl_xor(v, 1);
        v += __shfl_xor(v, 2);
        v += __shfl_xor(v, 4);
        v += __shfl_xor(v, 8);
        if (r16 == 0) atomicAdd(&rsp[row0 + r], v);
      }
    }
  } else if constexpr (EPI == 7) {
    bf16* C = (bf16*)Cv + (size_t)z * sC;
    const float* rsp = bias + (size_t)z * 4096;
#pragma unroll
    for (int a = 0; a < 4; ++a) {
      const int row0 = (int)tileM + wm * 64 + a * 16 + q4 * 4;
      float inv[4];
#pragma unroll
      for (int r = 0; r < 4; ++r) inv[r] = 1.0f / rsp[row0 + r];
#pragma unroll
      for (int ni = 0; ni < 4; ++ni) {
        const int col = (int)tileN + wn * 64 + ni * 16 + r16;
#pragma unroll
        for (int r = 0; r < 4; ++r)
          C[(size_t)(row0 + r) * ldc + col] = (bf16)(acc[a][ni][r] * inv[r]);
      }
    }
  } else {  // EPI == 1
    bf16* C = (bf16*)Cv + (size_t)z * sC;
#pragma unroll
    for (int a = 0; a < 4; ++a) {
      const int row0 = (int)tileM + wm * 64 + a * 16 + q4 * 4;
#pragma unroll
      for (int ni = 0; ni < 4; ++ni) {
        const int col = (int)tileN + wn * 64 + ni * 16 + r16;
        const float badd = bias[col];
#pragma unroll
        for (int r = 0; r < 4; ++r)
          C[(size_t)(row0 + r) * ldc + col] = (bf16)((acc[a][ni][r] + badd) * scale);
      }
    }
  }
}

// ---------------- 128^2 bt-GEMM (kept for small shapes G2/G3) ----------------
// EPI: 1 bf16 (acc + bias[col]) * scale; 2 bf16 + bias[row]
template <int EPI>
__global__ __launch_bounds__(256) void gemm_bt(
    const bf16* __restrict__ A, long long sA, int lda,
    const bf16* __restrict__ B, long long sB, int ldb,
    void* __restrict__ Cv, long long sC, int ldc, int K,
    const float* __restrict__ bias, float scale) {
  const int z = blockIdx.z;
  A += (size_t)z * sA;
  B += (size_t)z * sB;
  const int tid = threadIdx.x;
  const int w = tid >> 6, lane = tid & 63;
  const int r16 = lane & 15, q4 = lane >> 4;
  const long long tileM = (long long)blockIdx.x * 128;
  const long long tileN = (long long)blockIdx.y * 128;

  __shared__ bf16 As[2][128 * 32];
  __shared__ bf16 Bs[2][128 * 32];

  f32x4 acc[4][4] = {};

  const int srow = tid >> 2;
  const int soff = (tid & 3) * 16;
  const char* Ag0 = (const char*)A + ((size_t)(tileM + srow) * lda) * 2 + soff;
  const char* Bg0 = (const char*)B + ((size_t)(tileN + srow) * ldb) * 2 + soff;
  const size_t arow64 = (size_t)64 * lda * 2;
  const size_t brow64 = (size_t)64 * ldb * 2;

  auto stage = [&](int buf, int k0) {
    const char* a = Ag0 + (size_t)k0 * 2;
    const char* b = Bg0 + (size_t)k0 * 2;
    bf16* al = &As[buf][w * 512];
    bf16* bl = &Bs[buf][w * 512];
    GLOAD_LDS16(a, al);
    GLOAD_LDS16(a + arow64, al + 2048);
    GLOAD_LDS16(b, bl);
    GLOAD_LDS16(b + brow64, bl + 2048);
  };

  const int wr = (w >> 1) * 64, wc = (w & 1) * 64;
  const int nt = K >> 5;
  stage(0, 0);
  __syncthreads();
  int cur = 0;
  for (int t = 0; t < nt; ++t) {
    if (t + 1 < nt) stage(cur ^ 1, (t + 1) * 32);
    bf16x8 af[4], bfv[4];
#pragma unroll
    for (int f = 0; f < 4; ++f) {
      af[f]  = *(const bf16x8*)&As[cur][(wr + f * 16 + r16) * 32 + q4 * 8];
      bfv[f] = *(const bf16x8*)&Bs[cur][(wc + f * 16 + r16) * 32 + q4 * 8];
    }
#pragma unroll
    for (int i = 0; i < 4; ++i)
#pragma unroll
      for (int j = 0; j < 4; ++j)
        acc[i][j] = __builtin_amdgcn_mfma_f32_16x16x32_bf16(af[i], bfv[j], acc[i][j], 0, 0, 0);
    __syncthreads();
    cur ^= 1;
  }

  bf16* C = (bf16*)Cv + (size_t)z * sC;
#pragma unroll
  for (int i = 0; i < 4; ++i) {
    const int row0 = (int)tileM + wr + i * 16 + q4 * 4;
#pragma unroll
    for (int j = 0; j < 4; ++j) {
      const int col = (int)tileN + wc + j * 16 + r16;
      float badd = 0.f;
      if constexpr (EPI == 1) badd = bias[col];
#pragma unroll
      for (int r = 0; r < 4; ++r) {
        float v = acc[i][j][r];
        if constexpr (EPI == 1) v = (v + badd) * scale;
        if constexpr (EPI == 2) v += bias[row0 + r];
        C[(size_t)(row0 + r) * ldc + col] = (bf16)v;
      }
    }
  }
}

// ---------------- launch ----------------
extern "C" void kernel_launch(void* const* d_in, const int* in_sizes, int n_in,
                              void* d_out, int out_size, void* d_ws, size_t ws_size,
                              hipStream_t stream) {
  const float* x  = (const float*)d_in[0];
  const float* Wt = (const float*)d_in[1];
  const float* bt = (const float*)d_in[2];
  const float* Wp = (const float*)d_in[3];
  const float* bp = (const float*)d_in[4];
  const float* Wg = (const float*)d_in[5];
  const float* bg = (const float*)d_in[6];
  const float* Wo = (const float*)d_in[7];
  const float* bo = (const float*)d_in[8];
  float* out = (float*)d_out;

  const size_t MB = 1024ull * 1024ull;
  char* ws = (char*)d_ws;
  bf16* WtB = (bf16*)(ws + 0 * MB);
  bf16* WpB = (bf16*)(ws + 1 * MB);
  bf16* WgB = (bf16*)(ws + 2 * MB);
  bf16* WoB = (bf16*)(ws + 3 * MB);

  cast_f2b<<<512, 256, 0, stream>>>(Wt, WtB, 512 * 1024);
  cast_f2b<<<512, 256, 0, stream>>>(Wp, WpB, 512 * 1024);
  cast_f2b<<<512, 256, 0, stream>>>(Wg, WgB, 512 * 1024);
  cast_f2b<<<512, 256, 0, stream>>>(Wo, WoB, 1024 * 512);

  const float SCALE = 0.044194173824159216f;  // 512^-0.5, folded into theta

  auto run_g6 = [&](int nb, int b0, bf16* tT) {
    gemm256<4><<<dim3(8, 16, nb), 512, 0, stream>>>(WoB, 0, 512, tT, 4096ll * 512, 512,
                                                    out + (size_t)b0 * 1024 * 4096,
                                                    1024ll * 4096, 4096, 512,
                                                    bo, x + (size_t)b0 * 1024 * 4096,
                                                    1024ll * 4096, 1.f, nullptr);
  };

  if (ws_size >= 164 * MB) {
    bf16* pxT    = (bf16*)(ws + 4 * MB);     // 16MB
    bf16* phiT   = (bf16*)(ws + 20 * MB);    // 8MB
    bf16* g      = (bf16*)(ws + 28 * MB);    // 8MB
    bf16* thetaT = (bf16*)(ws + 36 * MB);    // 32MB
    bf16* tT     = (bf16*)(ws + 68 * MB);    // 32MB
    bf16* xbT    = (bf16*)(ws + 100 * MB);   // 64MB (staging only; no aliasing)
    bf16*  Pt   = (bf16*)d_out;                       // 64MB scratch in d_out
    float* rsum = (float*)((char*)d_out + 80 * MB);   // 128KB scratch in d_out

    prep_kernel<<<dim3(1024, 8), 256, 0, stream>>>(x, xbT, pxT);
    gemm256<1><<<dim3(32, 2, 8), 512, 0, stream>>>(xbT, 4096ll * 1024, 1024, WtB, 0, 1024,
                                                   thetaT, 4096ll * 512, 512, 1024,
                                                   bt, nullptr, 0, SCALE, nullptr);
    gemm_bt<1><<<dim3(8, 4, 8), 256, 0, stream>>>(pxT, 1024ll * 1024, 1024, WpB, 0, 1024,
                                                  phiT, 1024ll * 512, 512, 1024, bp, 1.f);
    gemm_bt<2><<<dim3(4, 8, 8), 256, 0, stream>>>(WgB, 0, 1024, pxT, 1024ll * 1024, 1024,
                                                  g, 512ll * 1024, 1024, 1024, bg, 1.f);
    zero_k<<<128, 256, 0, stream>>>(rsum, 32768);
    gemm256<5><<<dim3(32, 4, 8), 512, 0, stream>>>(thetaT, 4096ll * 512, 512,
                                                   phiT, 1024ll * 512, 512,
                                                   Pt, 4096ll * 1024, 1024, 512,
                                                   nullptr, nullptr, 0, 1.f, rsum);
    gemm256<7><<<dim3(32, 2, 8), 512, 0, stream>>>(Pt, 4096ll * 1024, 1024,
                                                   g, 512ll * 1024, 1024,
                                                   tT, 4096ll * 512, 512, 1024,
                                                   rsum, nullptr, 0, 1.f, nullptr);
    run_g6(8, 0, tT);
  } else if (ws_size >= 108 * MB) {
    bf16* pxT    = (bf16*)(ws + 4 * MB);
    bf16* phiT   = (bf16*)(ws + 20 * MB);
    bf16* g      = (bf16*)(ws + 28 * MB);
    bf16* thetaT = (bf16*)(ws + 36 * MB);
    bf16* tT     = (bf16*)(ws + 68 * MB);
    bf16* xbT    = (bf16*)(ws + 100 * MB);   // 8MB per-batch staging
    float* rsum = (float*)((char*)d_out + 80 * MB);
    for (int b = 0; b < 8; ++b) {
      prep_kernel<<<dim3(1024, 1), 256, 0, stream>>>(x + (size_t)b * 1024 * 4096, xbT,
                                                     pxT + (size_t)b * 1024 * 1024);
      gemm256<1><<<dim3(32, 2, 1), 512, 0, stream>>>(xbT, 0, 1024, WtB, 0, 1024,
                                                     thetaT + (size_t)b * 4096 * 512, 0, 512,
                                                     1024, bt, nullptr, 0, SCALE, nullptr);
    }
    gemm_bt<1><<<dim3(8, 4, 8), 256, 0, stream>>>(pxT, 1024ll * 1024, 1024, WpB, 0, 1024,
                                                  phiT, 1024ll * 512, 512, 1024, bp, 1.f);
    gemm_bt<2><<<dim3(4, 8, 8), 256, 0, stream>>>(WgB, 0, 1024, pxT, 1024ll * 1024, 1024,
                                                  g, 512ll * 1024, 1024, 1024, bg, 1.f);
    for (int b = 0; b < 8; ++b) {
      bf16* Ptb = (bf16*)d_out + (size_t)b * 4096 * 1024;
      zero_k<<<16, 256, 0, stream>>>(rsum + (size_t)b * 4096, 4096);
      gemm256<5><<<dim3(32, 4, 1), 512, 0, stream>>>(thetaT + (size_t)b * 4096 * 512, 0, 512,
                                                     phiT + (size_t)b * 1024 * 512, 0, 512,
                                                     Ptb, 0, 1024, 512,
                                                     nullptr, nullptr, 0, 1.f,
                                                     rsum + (size_t)b * 4096);
      gemm256<7><<<dim3(32, 2, 1), 512, 0, stream>>>(Ptb, 0, 1024,
                                                     g + (size_t)b * 512 * 1024, 0, 1024,
                                                     tT + (size_t)b * 4096 * 512, 0, 512, 1024,
                                                     rsum + (size_t)b * 4096, nullptr, 0, 1.f,
                                                     nullptr);
    }
    run_g6(8, 0, tT);
  } else {
    float* rsum  = (float*)(ws + 4 * MB);    // 16KB
    bf16* pxT    = (bf16*)(ws + 5 * MB);     // 2MB
    bf16* phiT   = (bf16*)(ws + 7 * MB);     // 1MB
    bf16* g      = (bf16*)(ws + 8 * MB);     // 1MB
    bf16* thetaT = (bf16*)(ws + 9 * MB);     // 4MB
    bf16* tT     = (bf16*)(ws + 13 * MB);    // 4MB
    bf16* Pt     = (bf16*)(ws + 17 * MB);    // 8MB
    bf16* xbT    = (bf16*)(ws + 25 * MB);    // 8MB -> 33MB total
    for (int b = 0; b < 8; ++b) {
      prep_kernel<<<dim3(1024, 1), 256, 0, stream>>>(x + (size_t)b * 1024 * 4096, xbT, pxT);
      gemm256<1><<<dim3(32, 2, 1), 512, 0, stream>>>(xbT, 0, 1024, WtB, 0, 1024,
                                                     thetaT, 0, 512, 1024,
                                                     bt, nullptr, 0, SCALE, nullptr);
      gemm_bt<1><<<dim3(8, 4, 1), 256, 0, stream>>>(pxT, 0, 1024, WpB, 0, 1024,
                                                    phiT, 0, 512, 1024, bp, 1.f);
      gemm_bt<2><<<dim3(4, 8, 1), 256, 0, stream>>>(WgB, 0, 1024, pxT, 0, 1024,
                                                    g, 0, 1024, 1024, bg, 1.f);
      zero_k<<<16, 256, 0, stream>>>(rsum, 4096);
      gemm256<5><<<dim3(32, 4, 1), 512, 0, stream>>>(thetaT, 0, 512, phiT, 0, 512,
                                                     Pt, 0, 1024, 512,
                                                     nullptr, nullptr, 0, 1.f, rsum);
      gemm256<7><<<dim3(32, 2, 1), 512, 0, stream>>>(Pt, 0, 1024, g, 0, 1024,
                                                     tT, 0, 512, 1024,
                                                     rsum, nullptr, 0, 1.f, nullptr);
      run_g6(1, b, tT);
    }
  }
}